// Round 4
// baseline (4211.614 us; speedup 1.0000x reference)
//
#include <hip/hip_runtime.h>
#include <stdint.h>

// Problem constants
#define BB   32      // batch
#define SS   512     // seq len
#define EE   256     // input dim
#define HH   256     // hidden
#define H4   1024    // 4*H
#define NTHR 512     // threads per WG (8 waves)

// one-exchange kernel geometry: 16 WGs per direction, 16 h-cols per WG
#define NSL  16

typedef short bf16x8 __attribute__((ext_vector_type(8)));
typedef float f32x4  __attribute__((ext_vector_type(4)));
typedef unsigned short u16x4 __attribute__((ext_vector_type(4)));
typedef unsigned long long ull;

// ---- one-exchange kernel LDS offsets ----
#define G_HF  0        // h A-frags, 16KB
#define G_SF  16384    // s A-frags, 16KB
#define G_ZB  32768    // z tiles f32 [8][16][17] = 8704
#define G_MB  41472    // mask [2][32] f32 + AO int[2]
#define G_SMEM 41744

// ---- fallback (round-1) kernel LDS offsets ----
#define O_HF  0
#define O_SF  16384
#define O_XB  32768
#define O_ZB  49152
#define O_US  57344
#define O_UH  59392
#define O_CB  61440
#define O_MB  63488
#define O_SMEM 63744

__device__ __forceinline__ float bf2f(uint32_t u) {
  union { uint32_t i; float f; } v; v.i = u << 16; return v.f;
}
__device__ __forceinline__ uint32_t f2bf(float f) {
  union { float f; uint32_t i; } v; v.f = f;
  return (v.i + 0x7fffu + ((v.i >> 16) & 1u)) >> 16;
}
__device__ __forceinline__ float sigm(float x) { return 1.f / (1.f + __expf(-x)); }
__device__ __forceinline__ float tanhfast(float x) {
  float e = __expf(2.f * x);
  return 1.f - 2.f / (1.f + e);
}
// byte offset of element (batch m, k) inside a 16KB A-fragment region
__device__ __forceinline__ int fragAddr(int m, int k) {
  return (((m >> 4) * 8 + (k >> 5)) << 10) + (((m & 15) + (((k >> 3) & 3) << 4)) << 4) + ((k & 7) << 1);
}
__device__ __forceinline__ f32x4 mfma16(bf16x8 a, bf16x8 b, f32x4 c) {
  return __builtin_amdgcn_mfma_f32_16x16x32_bf16(a, b, c, 0, 0, 0);
}

__global__ void init_flags(uint32_t* f) {
  int i = blockIdx.x * blockDim.x + threadIdx.x;
  if (i < 1024) f[i] = 0u;
}
__global__ void zero_words(uint32_t* p, int n) {
  int i = blockIdx.x * blockDim.x + threadIdx.x;
  if (i < n) p[i] = 0u;
}

// ============================================================================
// Pre-pass: XZ[dir][t][col][b] = (x[b,t,:] @ Wx + b)[col]  (bf16)  [proven r2/r3]
// ============================================================================
__global__ void __launch_bounds__(512)
xz_prepass(const float* __restrict__ x,
           const float* __restrict__ Wx_f, const float* __restrict__ b_f,
           const float* __restrict__ Wx_r, const float* __restrict__ b_r,
           unsigned short* __restrict__ xz) {
  __shared__ __align__(16) char smem[65536];
  const int bid = blockIdx.x;
  const int dir = bid >> 7;
  const int t0  = (bid & 127) * 4;
  const int tid = threadIdx.x;
  const int w = tid >> 6, lane = tid & 63;
  const int lr = lane & 15, lq = lane >> 4;
  const float* W  = dir ? Wx_r : Wx_f;
  const float* bv = dir ? b_r  : b_f;

  {
    const int bm = tid >> 4, e0 = (tid & 15) * 16;
    for (int tt = 0; tt < 4; ++tt) {
      const float* xs = x + ((size_t)bm * SS + (t0 + tt)) * EE + e0;
      float xr[16];
      #pragma unroll
      for (int i = 0; i < 16; ++i) xr[i] = xs[i];
      #pragma unroll
      for (int hfi = 0; hfi < 2; ++hfi) {
        bf16x8 vv;
        #pragma unroll
        for (int i = 0; i < 8; ++i) vv[i] = (short)f2bf(xr[hfi * 8 + i]);
        *(bf16x8*)(smem + tt * 16384 + fragAddr(bm, e0 + hfi * 8)) = vv;
      }
    }
  }
  __syncthreads();

  for (int j = 0; j < 8; ++j) {
    const int col = (w * 8 + j) * 16 + lr;
    const float breg = bv[col];
    f32x4 acc[4][2];
    #pragma unroll
    for (int tt = 0; tt < 4; ++tt)
      #pragma unroll
      for (int m = 0; m < 2; ++m) {
        acc[tt][m][0] = breg; acc[tt][m][1] = breg;
        acc[tt][m][2] = breg; acc[tt][m][3] = breg;
      }
    #pragma unroll
    for (int kk = 0; kk < 8; ++kk) {
      bf16x8 bfr;
      #pragma unroll
      for (int i = 0; i < 8; ++i)
        bfr[i] = (short)f2bf(W[(size_t)(kk * 32 + lq * 8 + i) * H4 + col]);
      #pragma unroll
      for (int tt = 0; tt < 4; ++tt) {
        bf16x8 a0 = *(const bf16x8*)(smem + tt * 16384 + (kk << 10) + lane * 16);
        bf16x8 a1 = *(const bf16x8*)(smem + tt * 16384 + ((8 + kk) << 10) + lane * 16);
        acc[tt][0] = mfma16(a0, bfr, acc[tt][0]);
        acc[tt][1] = mfma16(a1, bfr, acc[tt][1]);
      }
    }
    #pragma unroll
    for (int tt = 0; tt < 4; ++tt)
      #pragma unroll
      for (int m = 0; m < 2; ++m) {
        u16x4 pk;
        #pragma unroll
        for (int i = 0; i < 4; ++i) pk[i] = (unsigned short)f2bf(acc[tt][m][i]);
        *(u16x4*)(xz + (((size_t)dir * SS + (t0 + tt)) * H4 + col) * BB + m * 16 + lq * 4) = pk;
      }
  }
}

// ============================================================================
// ONE-exchange persistent kernel: 16 WGs/dir; full-width Us/Uh in registers;
// s computed locally in every WG -> the s-RTT is eliminated.
// ============================================================================
__global__ void __launch_bounds__(NTHR, 2)
slstm_fast3(const float* __restrict__ mask,
            const float* Wh_f, const float* Ws_f,
            const float* Us_f, const float* Uh_f, const float* bs_f,
            const float* Wh_r, const float* Ws_r,
            const float* Us_r, const float* Uh_r, const float* bs_r,
            const unsigned short* __restrict__ xz,
            float* __restrict__ out,
            uint32_t* __restrict__ flags,
            ull* __restrict__ hbuf) {
  __shared__ __align__(16) char smem[G_SMEM];

  const int bid = blockIdx.x;    // 0..31
  const int dir = bid >> 4;
  const int sid = bid & 15;      // h-slice: cols [sid*16, sid*16+16)
  const int tid = threadIdx.x;
  const int w = tid >> 6;
  const int lane = tid & 63;
  const int lr = lane & 15, lq = lane >> 4;
  const int mt = w & 1, q = w >> 1;     // z tile assignment: tile idx == w

  const float* Wh = dir ? Wh_r : Wh_f;
  const float* Ws = dir ? Ws_r : Ws_f;
  const float* Us = dir ? Us_r : Us_f;
  const float* Uh = dir ? Uh_r : Uh_f;
  const float* bs = dir ? bs_r : bs_f;

  uint32_t* flagH = flags + dir * (NSL * 16);         // [16sl][16pad]

  // ---- persistent weight fragments ----
  bf16x8 WhF[8], WsF[8];           // z slice: 1 tile/wave (gate q, cols sid*16+lr)
  {
    const int col = q * HH + sid * 16 + lr;
    #pragma unroll
    for (int kk = 0; kk < 8; ++kk) {
      bf16x8 vh, vs;
      #pragma unroll
      for (int i = 0; i < 8; ++i) {
        const int k = kk * 32 + lq * 8 + i;
        vh[i] = (short)f2bf(Wh[(size_t)k * H4 + col]);
        vs[i] = (short)f2bf(Ws[(size_t)k * H4 + col]);
      }
      WhF[kk] = vh; WsF[kk] = vs;
    }
  }
  bf16x8 UsF[2][8], UhF[2][8];     // full-width U: wave w owns n-slices {2w, 2w+1}
  float bsr[2];
  #pragma unroll
  for (int jnt = 0; jnt < 2; ++jnt) {
    const int colU = (2 * w + jnt) * 16 + lr;
    bsr[jnt] = bs[colU];
    #pragma unroll
    for (int kk = 0; kk < 8; ++kk) {
      bf16x8 vu, vh2;
      #pragma unroll
      for (int i = 0; i < 8; ++i) {
        const int k = kk * 32 + lq * 8 + i;
        vu[i]  = (short)f2bf(Us[(size_t)k * HH + colU]);
        vh2[i] = (short)f2bf(Uh[(size_t)k * HH + colU]);
      }
      UsF[jnt][kk] = vu; UhF[jnt][kk] = vh2;
    }
  }

  // ---- zero state (HF, SF) ----
  {
    uint4* p = (uint4*)smem;
    for (int i = tid; i < 2048; i += NTHR) p[i] = make_uint4(0u, 0u, 0u, 0u);
  }
  // ---- mask_0 / AO_0 / accZ_0 ----
  const int ta0 = dir ? (SS - 1) : 0;
  {
    float mr = 0.f;
    if (tid < 32) mr = mask[(size_t)tid * SS + ta0];
    if (w == 0) {
      if (tid < 32) ((float*)(smem + G_MB))[tid] = mr;
      bool p = (lane < 32) ? (mr == 1.f) : true;
      ull bal = __ballot(p);
      if (lane == 0) ((int*)(smem + G_MB + 256))[0] = (bal == ~0ull) ? 1 : 0;
    }
  }
  const int zcol = q * HH + sid * 16 + lr;
  float creg = 0.f;                 // c state: one element per thread
  f32x4 accZ;
  {
    u16x4 xa = *(const u16x4*)(xz + (((size_t)dir * SS + ta0) * H4 + zcol) * BB + mt * 16 + lq * 4);
    #pragma unroll
    for (int i = 0; i < 4; ++i) accZ[i] = bf2f(xa[i]);
  }
  __syncthreads();

  const int m  = tid >> 4, cc = tid & 15;   // gates mapping
  const int mtL = m >> 4, rr = m & 15;

  for (int t = 0; t < SS; ++t) {
    const int par = t & 1;
    const float* mb = (const float*)(smem + G_MB) + par * 32;
    const bool ao = ((const int*)(smem + G_MB + 256))[par] != 0;
    ull* hbufP = hbuf + ((size_t)(dir * 2 + par) * NSL + sid) * 128;

    // ---- (a) spill accZ (z_t slice) ----
    {
      float* zb = (float*)(smem + G_ZB);
      #pragma unroll
      for (int i = 0; i < 4; ++i)
        zb[(w * 16 + lq * 4 + i) * 17 + lr] = accZ[i];
    }
    __syncthreads();   // B1

    // ---- (b) gates + publish h_new ----
    float hbl, cbl;
    {
      const float* zb = (const float*)(smem + G_ZB);
      const float zi = zb[(((0 * 2 + mtL) * 16) + rr) * 17 + cc];
      const float zf = zb[(((1 * 2 + mtL) * 16) + rr) * 17 + cc];
      const float zg = zb[(((2 * 2 + mtL) * 16) + rr) * 17 + cc];
      const float zo = zb[(((3 * 2 + mtL) * 16) + rr) * 17 + cc];
      const float cn = sigm(zf) * creg + sigm(zi) * tanhfast(zg);
      const float hn = sigm(zo) * tanhfast(cn);
      if (ao) { cbl = cn; hbl = hn; }
      else {
        const float mval = mb[m];
        cbl = mval * cn + (1.f - mval) * creg;
        const float hold = bf2f(*(const uint16_t*)(smem + G_HF + fragAddr(m, sid * 16 + cc)));
        hbl = mval * hn + (1.f - mval) * hold;
      }
      creg = cbl;
      uint32_t hb = f2bf(hn);
      uint32_t pv1 = (uint32_t)__shfl_xor((int)hb, 1);
      uint32_t w0 = (hb & 0xffffu) | (pv1 << 16);
      uint32_t w0b = (uint32_t)__shfl_xor((int)w0, 2);
      if ((cc & 3) == 0) {
        ull q0 = ((ull)w0b << 32) | (ull)w0;
        __hip_atomic_store(&hbufP[m * 4 + (cc >> 2)], q0,
                           __ATOMIC_RELAXED, __HIP_MEMORY_SCOPE_AGENT);
      }
    }
    __syncthreads();   // B2 (drains the publish stores)
    if (tid == 0)
      __hip_atomic_store(&flagH[sid * 16], (uint32_t)(t + 1),
                         __ATOMIC_RELAXED, __HIP_MEMORY_SCOPE_AGENT);

    // ---- SHADOW (hides the h RTT) ----
    const int tact = dir ? (SS - 1 - t) : t;
    {
      const size_t ob = ((size_t)tact * BB + m) * (2 * HH) + (size_t)dir * HH + sid * 16 + cc;
      __builtin_nontemporal_store(hbl, &out[ob]);
      __builtin_nontemporal_store(cbl, &out[ob + 8388608]);
    }
    u16x4 nx = {0, 0, 0, 0};
    if (t + 1 < SS) {
      const int ta = dir ? (SS - 2 - t) : (t + 1);
      nx = *(const u16x4*)(xz + (((size_t)dir * SS + ta) * H4 + zcol) * BB + mt * 16 + lq * 4);
      float mr = 0.f;
      if (tid < 32) mr = mask[(size_t)tid * SS + ta];
      if (w == 0) {
        if (tid < 32) ((float*)(smem + G_MB))[(par ^ 1) * 32 + tid] = mr;
        bool p = (lane < 32) ? (mr == 1.f) : true;
        ull bal = __ballot(p);
        if (lane == 0) ((int*)(smem + G_MB + 256))[par ^ 1] = (bal == ~0ull) ? 1 : 0;
      }
    }
    // us = s_t @ Us (full-width)
    f32x4 accU[2][2];
    #pragma unroll
    for (int jnt = 0; jnt < 2; ++jnt)
      #pragma unroll
      for (int m2 = 0; m2 < 2; ++m2) {
        accU[jnt][m2][0] = 0.f; accU[jnt][m2][1] = 0.f;
        accU[jnt][m2][2] = 0.f; accU[jnt][m2][3] = 0.f;
      }
    #pragma unroll
    for (int kk = 0; kk < 8; ++kk) {
      bf16x8 as0 = *(const bf16x8*)(smem + G_SF + (kk << 10) + lane * 16);
      bf16x8 as1 = *(const bf16x8*)(smem + G_SF + ((8 + kk) << 10) + lane * 16);
      accU[0][0] = mfma16(as0, UsF[0][kk], accU[0][0]);
      accU[0][1] = mfma16(as1, UsF[0][kk], accU[0][1]);
      accU[1][0] = mfma16(as0, UsF[1][kk], accU[1][0]);
      accU[1][1] = mfma16(as1, UsF[1][kk], accU[1][1]);
    }

    // ---- poll + consume h_new (raw 16B/lane; stash old if blending) ----
    uint4 stash[2];
    {
      if (lane < 2) {
        while (__hip_atomic_load(&flagH[(2 * w + lane) * 16], __ATOMIC_RELAXED,
                                 __HIP_MEMORY_SCOPE_AGENT) < (uint32_t)(t + 1)) {}
      }
      #pragma unroll
      for (int ss2 = 0; ss2 < 2; ++ss2) {
        const int sl = 2 * w + ss2;
        const ull* src = hbuf + ((size_t)(dir * 2 + par) * NSL + sl) * 128;
        ull lo = __hip_atomic_load(&src[lane * 2],     __ATOMIC_RELAXED, __HIP_MEMORY_SCOPE_AGENT);
        ull hi = __hip_atomic_load(&src[lane * 2 + 1], __ATOMIC_RELAXED, __HIP_MEMORY_SCOPE_AGENT);
        const int m2 = lane >> 1, h8 = lane & 1;
        char* dst = smem + G_HF + (((m2 >> 4) * 8 + (sl >> 1)) << 10)
                                + (((m2 & 15) + 16 * ((sl * 2 + h8) & 3)) << 4);
        if (!ao) stash[ss2] = *(const uint4*)dst;
        uint4 nv;
        nv.x = (uint32_t)lo; nv.y = (uint32_t)(lo >> 32);
        nv.z = (uint32_t)hi; nv.w = (uint32_t)(hi >> 32);
        *(uint4*)dst = nv;
      }
    }
    __syncthreads();   // B3

    // ---- (e) uh = h_new @ Uh  (+ fused next-z Wh in fast path) ----
    f32x4 accZn;
    if (t + 1 < SS) {
      #pragma unroll
      for (int i = 0; i < 4; ++i) accZn[i] = bf2f(nx[i]);
    }
    const bool fuseWh = ao && (t + 1 < SS);
    #pragma unroll
    for (int kk = 0; kk < 8; ++kk) {
      bf16x8 an0 = *(const bf16x8*)(smem + G_HF + (kk << 10) + lane * 16);
      bf16x8 an1 = *(const bf16x8*)(smem + G_HF + ((8 + kk) << 10) + lane * 16);
      accU[0][0] = mfma16(an0, UhF[0][kk], accU[0][0]);
      accU[0][1] = mfma16(an1, UhF[0][kk], accU[0][1]);
      accU[1][0] = mfma16(an0, UhF[1][kk], accU[1][0]);
      accU[1][1] = mfma16(an1, UhF[1][kk], accU[1][1]);
      if (fuseWh) accZn = mfma16(mt ? an1 : an0, WhF[kk], accZn);
    }
    if (!ao) {         // generic: blend HF -> h_{t+1} (raw reads for Uh are done)
      __syncthreads();
      #pragma unroll
      for (int ss2 = 0; ss2 < 2; ++ss2) {
        const int sl = 2 * w + ss2;
        const int m2 = lane >> 1, h8 = lane & 1;
        char* dst = smem + G_HF + (((m2 >> 4) * 8 + (sl >> 1)) << 10)
                                + (((m2 & 15) + 16 * ((sl * 2 + h8) & 3)) << 4);
        uint4 nv = *(const uint4*)dst;
        const uint4 ov = stash[ss2];
        const float mv = mb[m2];
        #pragma unroll
        for (int e = 0; e < 4; ++e) {
          uint32_t nw = (&nv.x)[e], owd = (&ov.x)[e];
          float b0 = mv * bf2f(nw & 0xffffu) + (1.f - mv) * bf2f(owd & 0xffffu);
          float b1 = mv * bf2f(nw >> 16)     + (1.f - mv) * bf2f(owd >> 16);
          (&nv.x)[e] = (f2bf(b0) & 0xffffu) | (f2bf(b1) << 16);
        }
        *(uint4*)dst = nv;
      }
    }

    // ---- (f) s-tail: s_{t+1} = tanh(us + uh + bs); write SF; s_out ----
    #pragma unroll
    for (int jnt = 0; jnt < 2; ++jnt) {
      const int ksl = 2 * w + jnt;
      const int kbase = ksl * 16;
      const bool owner = (ksl == sid);
      #pragma unroll
      for (int m2 = 0; m2 < 2; ++m2) {
        #pragma unroll
        for (int i = 0; i < 4; ++i) {
          const int m3 = m2 * 16 + lq * 4 + i;
          float sn = tanhfast(accU[jnt][m2][i] + bsr[jnt]);
          if (!ao) {
            const float mv3 = mb[m3];
            const float sold = bf2f(*(const uint16_t*)(smem + G_SF + fragAddr(m3, kbase + lr)));
            sn = mv3 * sn + (1.f - mv3) * sold;
          }
          if (owner)
            __builtin_nontemporal_store(
                sn, &out[((size_t)tact * BB + m3) * (2 * HH) + (size_t)dir * HH + sid * 16 + lr + 16777216]);
          uint32_t sb = f2bf(sn);
          uint32_t pv = (uint32_t)__shfl_xor((int)sb, 1);
          if ((lr & 1) == 0)
            *(uint32_t*)(smem + G_SF + fragAddr(m3, kbase + lr)) = (sb & 0xffffu) | (pv << 16);
        }
      }
    }
    __syncthreads();   // B4

    // ---- (g) next z: accZn += s_{t+1} @ Ws  (+ Wh in generic path) ----
    if (t + 1 < SS) {
      #pragma unroll
      for (int kk = 0; kk < 8; ++kk) {
        bf16x8 as2 = *(const bf16x8*)(smem + G_SF + ((mt * 8 + kk) << 10) + lane * 16);
        accZn = mfma16(as2, WsF[kk], accZn);
      }
      if (!ao) {
        #pragma unroll
        for (int kk = 0; kk < 8; ++kk) {
          bf16x8 ah2 = *(const bf16x8*)(smem + G_HF + ((mt * 8 + kk) << 10) + lane * 16);
          accZn = mfma16(ah2, WhF[kk], accZn);
        }
      }
      accZ = accZn;
    }
  }
}

// ============================================================================
// Fallback: proven round-1 kernel (used only if ws too small).
// ============================================================================
__global__ void __launch_bounds__(NTHR)
slstm_persistent(const float* __restrict__ x, const float* __restrict__ mask,
                 const float* Wx_f, const float* Wh_f, const float* Ws_f, const float* b_f,
                 const float* Us_f, const float* Uh_f, const float* bs_f,
                 const float* Wx_r, const float* Wh_r, const float* Ws_r, const float* b_r,
                 const float* Us_r, const float* Uh_r, const float* bs_r,
                 float* __restrict__ out, uint32_t* __restrict__ wsbase) {
  __shared__ __align__(16) char smem[O_SMEM];

  const int bid = blockIdx.x;
  const int dir = bid >> 4;
  const int g   = bid & 15;
  const int tid = threadIdx.x;
  const int w    = tid >> 6;
  const int lane = tid & 63;
  const int lr = lane & 15, lq = lane >> 4;
  const int mt = w & 1;
  const int q  = w >> 1;

  const float* Wx = dir ? Wx_r : Wx_f;
  const float* Wh = dir ? Wh_r : Wh_f;
  const float* Ws = dir ? Ws_r : Ws_f;
  const float* bv = dir ? b_r  : b_f;
  const float* Us = dir ? Us_r : Us_f;
  const float* Uh = dir ? Uh_r : Uh_f;
  const float* bs = dir ? bs_r : bs_f;

  uint32_t* flags = wsbase;
  uint32_t* hbufB = wsbase + 1024;
  uint32_t* sbufB = wsbase + 1024 + 16384;
  uint32_t* flagH = flags + (dir * 2 + 0) * 16 * 16;
  uint32_t* flagS = flags + (dir * 2 + 1) * 16 * 16;

  bf16x8 WxF[8], WhF[8], WsF[8], UF[8];
  {
    const int col = q * HH + g * 16 + lr;
    #pragma unroll
    for (int kk = 0; kk < 8; ++kk) {
      bf16x8 vx, vh, vs;
      #pragma unroll
      for (int i = 0; i < 8; ++i) {
        int k = kk * 32 + lq * 8 + i;
        vx[i] = (short)f2bf(Wx[k * H4 + col]);
        vh[i] = (short)f2bf(Wh[k * H4 + col]);
        vs[i] = (short)f2bf(Ws[k * H4 + col]);
      }
      WxF[kk] = vx; WhF[kk] = vh; WsF[kk] = vs;
    }
  }
  if (w < 4) {
    const float* U = (w < 2) ? Us : Uh;
    const int colU = g * 16 + lr;
    #pragma unroll
    for (int kk = 0; kk < 8; ++kk) {
      bf16x8 vu;
      #pragma unroll
      for (int i = 0; i < 8; ++i) {
        int k = kk * 32 + lq * 8 + i;
        vu[i] = (short)f2bf(U[k * HH + colU]);
      }
      UF[kk] = vu;
    }
  }
  const float breg  = bv[q * HH + g * 16 + lr];
  const float bsreg = bs[g * 16 + (tid & 15)];

  {
    uint4* p = (uint4*)(smem);
    for (int i = tid; i < 2048; i += NTHR) p[i] = make_uint4(0u, 0u, 0u, 0u);
    float* cb = (float*)(smem + O_CB);
    for (int i = tid; i < BB * 16; i += NTHR) cb[i] = 0.f;
  }
  {
    const int ta = dir ? (SS - 1) : 0;
    const int bm = tid >> 4, e0 = (tid & 15) * 16;
    const float* xs = x + ((size_t)bm * SS + ta) * EE + e0;
    float xr0[16];
    #pragma unroll
    for (int i = 0; i < 16; ++i) xr0[i] = xs[i];
    #pragma unroll
    for (int hfi = 0; hfi < 2; ++hfi) {
      bf16x8 vv;
      #pragma unroll
      for (int i = 0; i < 8; ++i) vv[i] = (short)f2bf(xr0[hfi * 8 + i]);
      *(bf16x8*)(smem + O_XB + fragAddr(bm, e0 + hfi * 8)) = vv;
    }
    if (tid < BB) ((float*)(smem + O_MB))[tid] = mask[(size_t)tid * SS + ta];
  }
  __syncthreads();

  for (int t = 0; t < SS; ++t) {
    const int par = t & 1;
    uint32_t* HbufP = hbufB + (dir * 2 + par) * (16 * 256);
    uint32_t* SbufP = sbufB + (dir * 2 + par) * (16 * 256);
    const float* mb = (const float*)(smem + O_MB + par * 128);

    f32x4 accZ; accZ[0] = breg; accZ[1] = breg; accZ[2] = breg; accZ[3] = breg;
    f32x4 accU = {0.f, 0.f, 0.f, 0.f};
    #pragma unroll
    for (int kk = 0; kk < 8; ++kk) {
      const int fb = ((mt * 8 + kk) << 10) + lane * 16;
      bf16x8 ah = *(const bf16x8*)(smem + O_HF + fb);
      bf16x8 as = *(const bf16x8*)(smem + O_SF + fb);
      bf16x8 ax = *(const bf16x8*)(smem + O_XB + fb);
      accZ = mfma16(ax, WxF[kk], accZ);
      accZ = mfma16(ah, WhF[kk], accZ);
      accZ = mfma16(as, WsF[kk], accZ);
      if (w < 2) accU = mfma16(as, UF[kk], accU);
    }

    float xr[16]; float mreg = 0.f;
    if (t + 1 < SS) {
      const int ta = dir ? (SS - 2 - t) : (t + 1);
      const int bm = tid >> 4, e0 = (tid & 15) * 16;
      const float* xs = x + ((size_t)bm * SS + ta) * EE + e0;
      #pragma unroll
      for (int i = 0; i < 16; ++i) xr[i] = xs[i];
      if (tid < BB) mreg = mask[(size_t)tid * SS + ta];
    }

    {
      float* zb = (float*)(smem + O_ZB);
      #pragma unroll
      for (int i = 0; i < 4; ++i)
        zb[(mt * 4 + q) * 256 + (lq * 4 + i) * 16 + lr] = accZ[i];
      if (w < 2) {
        float* ub = (float*)(smem + O_US);
        #pragma unroll
        for (int i = 0; i < 4; ++i)
          ub[mt * 256 + (lq * 4 + i) * 16 + lr] = accU[i];
      }
    }
    __syncthreads();

    const int bm = tid >> 4, cc = tid & 15;
    const int mtL = bm >> 4, rr = bm & 15;
    float mval;
    {
      const float* zb = (const float*)(smem + O_ZB);
      float zi = zb[(mtL * 4 + 0) * 256 + rr * 16 + cc];
      float zf = zb[(mtL * 4 + 1) * 256 + rr * 16 + cc];
      float zg = zb[(mtL * 4 + 2) * 256 + rr * 16 + cc];
      float zo = zb[(mtL * 4 + 3) * 256 + rr * 16 + cc];
      float* cb = (float*)(smem + O_CB);
      float cold = cb[bm * 16 + cc];
      mval = mb[bm];
      float cn = sigm(zf) * cold + sigm(zi) * tanhfast(zg);
      float hnew = sigm(zo) * tanhfast(cn);
      float cbl = mval * cn + (1.f - mval) * cold;
      cb[bm * 16 + cc] = cbl;
      float hold = bf2f(*(const uint16_t*)(smem + O_HF + fragAddr(bm, g * 16 + cc)));
      float hbl = mval * hnew + (1.f - mval) * hold;
      const int tact = dir ? (SS - 1 - t) : t;
      size_t ob = ((size_t)tact * BB + bm) * (2 * HH) + (size_t)dir * HH + g * 16 + cc;
      out[ob] = hbl;
      out[ob + 8388608] = cbl;
      uint32_t hb = f2bf(hnew);
      uint32_t pv = (uint32_t)__shfl_xor((int)hb, 1);
      if ((tid & 1) == 0) {
        uint32_t word = (hb & 0xffffu) | (pv << 16);
        __hip_atomic_store(&HbufP[g * 256 + (tid >> 1)], word,
                           __ATOMIC_RELAXED, __HIP_MEMORY_SCOPE_AGENT);
      }
    }
    __syncthreads();
    if (tid == 0)
      __hip_atomic_store(&flagH[g * 16], (uint32_t)(t + 1),
                         __ATOMIC_RELAXED, __HIP_MEMORY_SCOPE_AGENT);

    uint32_t oldw[2][4];
    #pragma unroll
    for (int ssl = 0; ssl < 2; ++ssl) {
      const int sl = w + ssl * 8;
      if (lane == 0) {
        while (__hip_atomic_load(&flagH[sl * 16], __ATOMIC_RELAXED,
                                 __HIP_MEMORY_SCOPE_AGENT) < (uint32_t)(t + 1)) {}
      }
      const uint32_t* src = HbufP + sl * 256;
      #pragma unroll
      for (int ww = 0; ww < 4; ++ww) {
        const int word = ww * 64 + lane;
        uint32_t v = __hip_atomic_load(&src[word], __ATOMIC_RELAXED, __HIP_MEMORY_SCOPE_AGENT);
        const int mrow = word >> 3, c0 = (word & 7) * 2;
        const int fa = fragAddr(mrow, sl * 16 + c0);
        oldw[ssl][ww] = *(uint32_t*)(smem + O_HF + fa);
        *(uint32_t*)(smem + O_HF + fa) = v;
      }
    }
    __syncthreads();

    if (w == 2 || w == 3) {
      f32x4 aU = {0.f, 0.f, 0.f, 0.f};
      #pragma unroll
      for (int kk = 0; kk < 8; ++kk) {
        bf16x8 ah = *(const bf16x8*)(smem + O_HF + (((w & 1) * 8 + kk) << 10) + lane * 16);
        aU = mfma16(ah, UF[kk], aU);
      }
      float* ub = (float*)(smem + O_UH);
      #pragma unroll
      for (int i = 0; i < 4; ++i)
        ub[(w & 1) * 256 + (lq * 4 + i) * 16 + lr] = aU[i];
    }
    __syncthreads();

    #pragma unroll
    for (int ssl = 0; ssl < 2; ++ssl) {
      const int sl = w + ssl * 8;
      #pragma unroll
      for (int ww = 0; ww < 4; ++ww) {
        const int word = ww * 64 + lane;
        const int mrow = word >> 3, c0 = (word & 7) * 2;
        const int fa = fragAddr(mrow, sl * 16 + c0);
        uint32_t nv = *(uint32_t*)(smem + O_HF + fa);
        uint32_t ov = oldw[ssl][ww];
        float mv = mb[mrow];
        float b0 = mv * bf2f(nv & 0xffffu) + (1.f - mv) * bf2f(ov & 0xffffu);
        float b1 = mv * bf2f(nv >> 16)     + (1.f - mv) * bf2f(ov >> 16);
        *(uint32_t*)(smem + O_HF + fa) = (f2bf(b0) & 0xffffu) | (f2bf(b1) << 16);
      }
    }
    {
      const float* ub1 = (const float*)(smem + O_US);
      const float* ub2 = (const float*)(smem + O_UH);
      float sv = ub1[mtL * 256 + rr * 16 + cc] + ub2[mtL * 256 + rr * 16 + cc] + bsreg;
      float snew = tanhfast(sv);
      float sold = bf2f(*(const uint16_t*)(smem + O_SF + fragAddr(bm, g * 16 + cc)));
      float sbl = mval * snew + (1.f - mval) * sold;
      const int tact = dir ? (SS - 1 - t) : t;
      out[((size_t)tact * BB + bm) * (2 * HH) + (size_t)dir * HH + g * 16 + cc + 16777216] = sbl;
      uint32_t sb = f2bf(snew);
      uint32_t pv = (uint32_t)__shfl_xor((int)sb, 1);
      if ((tid & 1) == 0) {
        uint32_t word = (sb & 0xffffu) | (pv << 16);
        __hip_atomic_store(&SbufP[g * 256 + (tid >> 1)], word,
                           __ATOMIC_RELAXED, __HIP_MEMORY_SCOPE_AGENT);
      }
    }
    __syncthreads();
    if (tid == 0)
      __hip_atomic_store(&flagS[g * 16], (uint32_t)(t + 1),
                         __ATOMIC_RELAXED, __HIP_MEMORY_SCOPE_AGENT);

    #pragma unroll
    for (int ssl = 0; ssl < 2; ++ssl) {
      const int sl = w + ssl * 8;
      if (lane == 0) {
        while (__hip_atomic_load(&flagS[sl * 16], __ATOMIC_RELAXED,
                                 __HIP_MEMORY_SCOPE_AGENT) < (uint32_t)(t + 1)) {}
      }
      const uint32_t* src = SbufP + sl * 256;
      #pragma unroll
      for (int ww = 0; ww < 4; ++ww) {
        const int word = ww * 64 + lane;
        uint32_t v = __hip_atomic_load(&src[word], __ATOMIC_RELAXED, __HIP_MEMORY_SCOPE_AGENT);
        const int mrow = word >> 3, c0 = (word & 7) * 2;
        const int fa = fragAddr(mrow, sl * 16 + c0);
        uint32_t ov = *(uint32_t*)(smem + O_SF + fa);
        float mv = mb[mrow];
        float b0 = mv * bf2f(v & 0xffffu) + (1.f - mv) * bf2f(ov & 0xffffu);
        float b1 = mv * bf2f(v >> 16)     + (1.f - mv) * bf2f(ov >> 16);
        *(uint32_t*)(smem + O_SF + fa) = (f2bf(b0) & 0xffffu) | (f2bf(b1) << 16);
      }
    }
    if (t + 1 < SS) {
      const int bm2 = tid >> 4, e0 = (tid & 15) * 16;
      #pragma unroll
      for (int hfi = 0; hfi < 2; ++hfi) {
        bf16x8 vv;
        #pragma unroll
        for (int i = 0; i < 8; ++i) vv[i] = (short)f2bf(xr[hfi * 8 + i]);
        *(bf16x8*)(smem + O_XB + fragAddr(bm2, e0 + hfi * 8)) = vv;
      }
      float* mbn = (float*)(smem + O_MB + ((t + 1) & 1) * 128);
      if (tid < BB) mbn[tid] = mreg;
    }
    __syncthreads();
  }
}

extern "C" void kernel_launch(void* const* d_in, const int* in_sizes, int n_in,
                              void* d_out, int out_size, void* d_ws, size_t ws_size,
                              hipStream_t stream) {
  (void)in_sizes; (void)n_in; (void)out_size;
  const float* x    = (const float*)d_in[0];
  const float* mask = (const float*)d_in[1];
  const float* Wx_f = (const float*)d_in[3];
  const float* Wh_f = (const float*)d_in[4];
  const float* Ws_f = (const float*)d_in[5];
  const float* b_f  = (const float*)d_in[6];
  const float* Us_f = (const float*)d_in[7];
  const float* Uh_f = (const float*)d_in[8];
  const float* bs_f = (const float*)d_in[9];
  const float* Wx_r = (const float*)d_in[10];
  const float* Wh_r = (const float*)d_in[11];
  const float* Ws_r = (const float*)d_in[12];
  const float* b_r  = (const float*)d_in[13];
  const float* Us_r = (const float*)d_in[14];
  const float* Uh_r = (const float*)d_in[15];
  const float* bs_r = (const float*)d_in[16];
  float* out = (float*)d_out;
  uint32_t* ws = (uint32_t*)d_ws;

  const size_t XZ_WORDS = (size_t)2 * SS * H4 * BB / 2;   // 16777216 u32 (bf16 xz)
  const size_t FLAG_WORDS = 512;
  const size_t HBUF_ULL = (size_t)2 * 2 * NSL * 128;      // 8192 ull
  const size_t need = (XZ_WORDS + FLAG_WORDS) * 4 + HBUF_ULL * 8;

  if (ws_size >= need) {
    unsigned short* xz = (unsigned short*)ws;
    uint32_t* flags = ws + XZ_WORDS;
    ull* hbuf = (ull*)(ws + XZ_WORDS + FLAG_WORDS);
    zero_words<<<dim3(1), dim3(512), 0, stream>>>(flags, (int)FLAG_WORDS);
    xz_prepass<<<dim3(256), dim3(512), 0, stream>>>(x, Wx_f, b_f, Wx_r, b_r, xz);
    slstm_fast3<<<dim3(32), dim3(NTHR), 0, stream>>>(
        mask, Wh_f, Ws_f, Us_f, Uh_f, bs_f,
        Wh_r, Ws_r, Us_r, Uh_r, bs_r, xz, out, flags, hbuf);
  } else {
    init_flags<<<dim3(4), dim3(256), 0, stream>>>(ws);
    slstm_persistent<<<dim3(32), dim3(NTHR), 0, stream>>>(
        x, mask, Wx_f, Wh_f, Ws_f, b_f, Us_f, Uh_f, bs_f,
        Wx_r, Wh_r, Ws_r, b_r, Us_r, Uh_r, bs_r, out, ws);
  }
}

// Round 5
// 2576.184 us; speedup vs baseline: 1.6348x; 1.6348x over previous
//
#include <hip/hip_runtime.h>
#include <stdint.h>

// Problem constants
#define BB   32      // batch
#define SS   512     // seq len
#define EE   256     // input dim
#define HH   256     // hidden
#define H4   1024    // 4*H
#define NTHR 512     // threads per WG (8 waves)

#define NSD  8       // WGs (slices) per direction
#define SW   32      // h-cols per slice

typedef short bf16x8 __attribute__((ext_vector_type(8)));
typedef float f32x4  __attribute__((ext_vector_type(4)));
typedef unsigned short u16x4 __attribute__((ext_vector_type(4)));
typedef unsigned long long ull;

// ---- fast4 LDS offsets ----
#define F_HF  0        // h A-frags, 16KB
#define F_SF  16384    // s A-frags, 16KB
#define F_ZB  32768    // z tiles f32 [8][16][33] = 16896 B
#define F_US  49664    // s@Us f32 [32][33]
#define F_UH  53888    // hnew@Uh f32 [32][33]
#define F_MB  58112    // mask [2][32] f32 + AO int[2]
#define F_SMEM 58384

// ---- fallback (round-1) kernel LDS offsets ----
#define O_HF  0
#define O_SF  16384
#define O_XB  32768
#define O_ZB  49152
#define O_US  57344
#define O_UH  59392
#define O_CB  61440
#define O_MB  63488
#define O_SMEM 63744

__device__ __forceinline__ float bf2f(uint32_t u) {
  union { uint32_t i; float f; } v; v.i = u << 16; return v.f;
}
__device__ __forceinline__ uint32_t f2bf(float f) {
  union { float f; uint32_t i; } v; v.f = f;
  return (v.i + 0x7fffu + ((v.i >> 16) & 1u)) >> 16;
}
__device__ __forceinline__ float sigm(float x) { return 1.f / (1.f + __expf(-x)); }
__device__ __forceinline__ float tanhfast(float x) {
  float e = __expf(2.f * x);
  return 1.f - 2.f / (1.f + e);
}
__device__ __forceinline__ int fragAddr(int m, int k) {
  return (((m >> 4) * 8 + (k >> 5)) << 10) + (((m & 15) + (((k >> 3) & 3) << 4)) << 4) + ((k & 7) << 1);
}
__device__ __forceinline__ f32x4 mfma16(bf16x8 a, bf16x8 b, f32x4 c) {
  return __builtin_amdgcn_mfma_f32_16x16x32_bf16(a, b, c, 0, 0, 0);
}
__device__ __forceinline__ uint32_t blend2(uint32_t nw, uint32_t ow, float mv) {
  float b0 = mv * bf2f(nw & 0xffffu) + (1.f - mv) * bf2f(ow & 0xffffu);
  float b1 = mv * bf2f(nw >> 16)     + (1.f - mv) * bf2f(ow >> 16);
  return (f2bf(b0) & 0xffffu) | (f2bf(b1) << 16);
}

// ---- tagged exchange: word = {v0|tag<<16, v1|tag<<16}; v0 = col cc, v1 = col cc+16 ----
// consume one slice (512 ull) into A-frag region; poll until all tags == tg.
__device__ __forceinline__ void consume_tagged(const ull* __restrict__ src,
                                               char* dstBase, int sl, int lane, uint32_t tg,
                                               bool blendNow, const float* mbv,
                                               bool doStash, uint32_t* stash) {
  const int Lg = lane >> 3;
  const int c0 = (lane & 7) * 2;
  ull dA[4], dB[4];
  bool ok = false;
  while (!ok) {
    ok = true;
    #pragma unroll
    for (int i = 0; i < 4; ++i) {
      const int W = i * 128 + lane * 2;
      dA[i] = __hip_atomic_load(&src[W],     __ATOMIC_RELAXED, __HIP_MEMORY_SCOPE_AGENT);
      dB[i] = __hip_atomic_load(&src[W + 1], __ATOMIC_RELAXED, __HIP_MEMORY_SCOPE_AGENT);
    }
    #pragma unroll
    for (int i = 0; i < 4; ++i) {
      ok &= (((uint32_t)(dA[i] >> 16) & 0xffffu) == tg) & ((uint32_t)(dA[i] >> 48) == tg);
      ok &= (((uint32_t)(dB[i] >> 16) & 0xffffu) == tg) & ((uint32_t)(dB[i] >> 48) == tg);
    }
  }
  #pragma unroll
  for (int i = 0; i < 4; ++i) {
    const int m = i * 8 + Lg;
    uint32_t wa = ((uint32_t)dA[i] & 0xffffu) | (((uint32_t)dB[i] & 0xffffu) << 16);
    uint32_t wb = ((uint32_t)(dA[i] >> 32) & 0xffffu) | (((uint32_t)(dB[i] >> 32) & 0xffffu) << 16);
    char* pa = dstBase + (((m >> 4) * 8 + sl) << 10) + (((m & 15) + 16 * (c0 >> 3)) << 4) + (c0 & 7) * 2;
    char* pb = pa + 512;
    if (doStash) { stash[i * 2] = *(const uint32_t*)pa; stash[i * 2 + 1] = *(const uint32_t*)pb; }
    if (blendNow) {
      const float mv = mbv[m];
      wa = blend2(wa, *(const uint32_t*)pa, mv);
      wb = blend2(wb, *(const uint32_t*)pb, mv);
    }
    *(uint32_t*)pa = wa;
    *(uint32_t*)pb = wb;
  }
}

__device__ __forceinline__ void reblend_tagged(char* dstBase, int sl, int lane,
                                               const float* mbv, const uint32_t* stash) {
  const int Lg = lane >> 3;
  const int c0 = (lane & 7) * 2;
  #pragma unroll
  for (int i = 0; i < 4; ++i) {
    const int m = i * 8 + Lg;
    char* pa = dstBase + (((m >> 4) * 8 + sl) << 10) + (((m & 15) + 16 * (c0 >> 3)) << 4) + (c0 & 7) * 2;
    char* pb = pa + 512;
    const float mv = mbv[m];
    *(uint32_t*)pa = blend2(*(const uint32_t*)pa, stash[i * 2],     mv);
    *(uint32_t*)pb = blend2(*(const uint32_t*)pb, stash[i * 2 + 1], mv);
  }
}

__global__ void init_flags(uint32_t* f) {
  int i = blockIdx.x * blockDim.x + threadIdx.x;
  if (i < 1024) f[i] = 0u;
}
__global__ void zero_words(uint32_t* p, int n) {
  int i = blockIdx.x * blockDim.x + threadIdx.x;
  if (i < n) p[i] = 0u;
}

// ============================================================================
// Pre-pass: XZ[dir][t][col][b] = (x[b,t,:] @ Wx + b)[col]  (bf16)  [proven]
// ============================================================================
__global__ void __launch_bounds__(512)
xz_prepass(const float* __restrict__ x,
           const float* __restrict__ Wx_f, const float* __restrict__ b_f,
           const float* __restrict__ Wx_r, const float* __restrict__ b_r,
           unsigned short* __restrict__ xz) {
  __shared__ __align__(16) char smem[65536];
  const int bid = blockIdx.x;
  const int dir = bid >> 7;
  const int t0  = (bid & 127) * 4;
  const int tid = threadIdx.x;
  const int w = tid >> 6, lane = tid & 63;
  const int lr = lane & 15, lq = lane >> 4;
  const float* W  = dir ? Wx_r : Wx_f;
  const float* bv = dir ? b_r  : b_f;

  {
    const int bm = tid >> 4, e0 = (tid & 15) * 16;
    for (int tt = 0; tt < 4; ++tt) {
      const float* xs = x + ((size_t)bm * SS + (t0 + tt)) * EE + e0;
      float xr[16];
      #pragma unroll
      for (int i = 0; i < 16; ++i) xr[i] = xs[i];
      #pragma unroll
      for (int hfi = 0; hfi < 2; ++hfi) {
        bf16x8 vv;
        #pragma unroll
        for (int i = 0; i < 8; ++i) vv[i] = (short)f2bf(xr[hfi * 8 + i]);
        *(bf16x8*)(smem + tt * 16384 + fragAddr(bm, e0 + hfi * 8)) = vv;
      }
    }
  }
  __syncthreads();

  for (int j = 0; j < 8; ++j) {
    const int col = (w * 8 + j) * 16 + lr;
    const float breg = bv[col];
    f32x4 acc[4][2];
    #pragma unroll
    for (int tt = 0; tt < 4; ++tt)
      #pragma unroll
      for (int m = 0; m < 2; ++m) {
        acc[tt][m][0] = breg; acc[tt][m][1] = breg;
        acc[tt][m][2] = breg; acc[tt][m][3] = breg;
      }
    #pragma unroll
    for (int kk = 0; kk < 8; ++kk) {
      bf16x8 bfr;
      #pragma unroll
      for (int i = 0; i < 8; ++i)
        bfr[i] = (short)f2bf(W[(size_t)(kk * 32 + lq * 8 + i) * H4 + col]);
      #pragma unroll
      for (int tt = 0; tt < 4; ++tt) {
        bf16x8 a0 = *(const bf16x8*)(smem + tt * 16384 + (kk << 10) + lane * 16);
        bf16x8 a1 = *(const bf16x8*)(smem + tt * 16384 + ((8 + kk) << 10) + lane * 16);
        acc[tt][0] = mfma16(a0, bfr, acc[tt][0]);
        acc[tt][1] = mfma16(a1, bfr, acc[tt][1]);
      }
    }
    #pragma unroll
    for (int tt = 0; tt < 4; ++tt)
      #pragma unroll
      for (int m = 0; m < 2; ++m) {
        u16x4 pk;
        #pragma unroll
        for (int i = 0; i < 4; ++i) pk[i] = (unsigned short)f2bf(acc[tt][m][i]);
        *(u16x4*)(xz + (((size_t)dir * SS + (t0 + tt)) * H4 + col) * BB + m * 16 + lq * 4) = pk;
      }
  }
}

// ============================================================================
// fast4: R3 dataflow (8 WGs/dir, 2 hops) + tagged flagless exchange,
// 4 barriers/step fast path, own-slice shortcuts, c-state in registers.
// ============================================================================
__global__ void __launch_bounds__(NTHR)
slstm_fast4(const float* __restrict__ mask,
            const float* Wh_f, const float* Ws_f,
            const float* Us_f, const float* Uh_f, const float* bs_f,
            const float* Wh_r, const float* Ws_r,
            const float* Us_r, const float* Uh_r, const float* bs_r,
            const unsigned short* __restrict__ xz,
            float* __restrict__ out,
            ull* __restrict__ hT, ull* __restrict__ sT) {
  __shared__ __align__(16) char smem[F_SMEM];

  const int bid = blockIdx.x;    // 0..15
  const int dir = bid >> 3;
  const int sid = bid & 7;       // slice: cols [sid*32, sid*32+32)
  const int tid = threadIdx.x;
  const int w = tid >> 6;
  const int lane = tid & 63;
  const int lr = lane & 15, lq = lane >> 4;
  const int mt = w & 1, q = w >> 1;

  const float* Wh = dir ? Wh_r : Wh_f;
  const float* Ws = dir ? Ws_r : Ws_f;
  const float* Us = dir ? Us_r : Us_f;
  const float* Uh = dir ? Uh_r : Uh_f;
  const float* bs = dir ? bs_r : bs_f;

  // ---- persistent weight fragments ----
  bf16x8 WhF[2][8], WsF[2][8], UF[8];
  #pragma unroll
  for (int nt = 0; nt < 2; ++nt) {
    const int col = q * HH + sid * SW + nt * 16 + lr;
    #pragma unroll
    for (int kk = 0; kk < 8; ++kk) {
      bf16x8 vh, vs;
      #pragma unroll
      for (int i = 0; i < 8; ++i) {
        const int k = kk * 32 + lq * 8 + i;
        vh[i] = (short)f2bf(Wh[(size_t)k * H4 + col]);
        vs[i] = (short)f2bf(Ws[(size_t)k * H4 + col]);
      }
      WhF[nt][kk] = vh; WsF[nt][kk] = vs;
    }
  }
  const int mtU = (w & 3) >> 1, ntU = w & 1;
  {
    const float* U = (w < 4) ? Us : Uh;
    const int colU = sid * SW + ntU * 16 + lr;
    #pragma unroll
    for (int kk = 0; kk < 8; ++kk) {
      bf16x8 vu;
      #pragma unroll
      for (int i = 0; i < 8; ++i) {
        const int k = kk * 32 + lq * 8 + i;
        vu[i] = (short)f2bf(U[(size_t)k * HH + colU]);
      }
      UF[kk] = vu;
    }
  }
  const float bs0 = bs[sid * SW + (tid & 15)];
  const float bs1 = bs[sid * SW + (tid & 15) + 16];

  // ---- zero HF/SF ----
  {
    uint4* p = (uint4*)smem;
    for (int i = tid; i < 2048; i += NTHR) p[i] = make_uint4(0u, 0u, 0u, 0u);
  }
  // ---- mask_0 / AO_0 / accZ_0 ----
  const int ta0 = dir ? (SS - 1) : 0;
  {
    float mr = 0.f;
    if (tid < 32) mr = mask[(size_t)tid * SS + ta0];
    if (w == 0) {
      if (tid < 32) ((float*)(smem + F_MB))[tid] = mr;
      bool p = (lane < 32) ? (mr == 1.f) : true;
      ull bal = __ballot(p);
      if (lane == 0) ((int*)(smem + F_MB + 256))[0] = (bal == ~0ull) ? 1 : 0;
    }
  }
  const int zc0 = q * HH + sid * SW + lr;
  f32x4 accZ0, accZ1;
  {
    u16x4 xa = *(const u16x4*)(xz + (((size_t)dir * SS + ta0) * H4 + zc0) * BB + mt * 16 + lq * 4);
    u16x4 xb = *(const u16x4*)(xz + (((size_t)dir * SS + ta0) * H4 + zc0 + 16) * BB + mt * 16 + lq * 4);
    #pragma unroll
    for (int i = 0; i < 4; ++i) { accZ0[i] = bf2f(xa[i]); accZ1[i] = bf2f(xb[i]); }
  }
  float c0reg = 0.f, c1reg = 0.f;
  __syncthreads();

  const int m = tid >> 4, cc = tid & 15;
  const int mtL = m >> 4, rr = m & 15;

  for (int t = 0; t < SS; ++t) {
    const int par = t & 1;
    const float* mb  = (const float*)(smem + F_MB) + par * 32;
    const float* mbp = (const float*)(smem + F_MB) + (par ^ 1) * 32;
    const bool ao  = ((const int*)(smem + F_MB + 256))[par] != 0;
    const bool aop = ((const int*)(smem + F_MB + 256))[par ^ 1] != 0;

    // ---- [A] consume s_t (tag t), skip own slice ----
    if (t > 0 && w != sid) {
      const ull* src = sT + (size_t)(dir * NSD + w) * 512;
      consume_tagged(src, smem + F_SF, w, lane, (uint32_t)t, !aop, mbp, false, nullptr);
    }
    __syncthreads();   // B1

    // ---- [B] accZ += s_t @ Ws ; spill z ----
    #pragma unroll
    for (int kk = 0; kk < 8; ++kk) {
      bf16x8 as = *(const bf16x8*)(smem + F_SF + ((mt * 8 + kk) << 10) + lane * 16);
      accZ0 = mfma16(as, WsF[0][kk], accZ0);
      accZ1 = mfma16(as, WsF[1][kk], accZ1);
    }
    {
      float* zb = (float*)(smem + F_ZB);
      const int base = (mt * 4 + q) * 528;
      #pragma unroll
      for (int i = 0; i < 4; ++i) {
        zb[base + (lq * 4 + i) * 33 + lr]      = accZ0[i];
        zb[base + (lq * 4 + i) * 33 + 16 + lr] = accZ1[i];
      }
    }
    __syncthreads();   // B2

    // ---- [C] gates + tagged publish h_new (+ own HF write in fast path) ----
    float hbl0, hbl1;
    {
      const float* zb = (const float*)(smem + F_ZB);
      float hn0, hn1;
      #pragma unroll
      for (int half = 0; half < 2; ++half) {
        const int n = cc + half * 16;
        const float zi = zb[(0 * 2 + mtL) * 2 * 528 / 2 + 0]; // placeholder (replaced below)
        (void)zi;
        const float z_i = zb[(mtL * 4 + 0) * 528 + rr * 33 + n];
        const float z_f = zb[(mtL * 4 + 1) * 528 + rr * 33 + n];
        const float z_g = zb[(mtL * 4 + 2) * 528 + rr * 33 + n];
        const float z_o = zb[(mtL * 4 + 3) * 528 + rr * 33 + n];
        const float cold = half ? c1reg : c0reg;
        const float cn = sigm(z_f) * cold + sigm(z_i) * tanhfast(z_g);
        const float hn = sigm(z_o) * tanhfast(cn);
        float cblv, hblv;
        if (ao) { cblv = cn; hblv = hn; }
        else {
          const float mval = mb[m];
          cblv = mval * cn + (1.f - mval) * cold;
          const float hold = bf2f(*(const uint16_t*)(smem + F_HF + fragAddr(m, sid * SW + n)));
          hblv = mval * hn + (1.f - mval) * hold;
        }
        if (half == 0) { c0reg = cblv; hn0 = hn; hbl0 = hblv; }
        else           { c1reg = cblv; hn1 = hn; hbl1 = hblv; }
      }
      const uint32_t tg = (uint32_t)(t + 1);
      ull pub = (ull)((f2bf(hn0) & 0xffffu) | (tg << 16))
              | ((ull)((f2bf(hn1) & 0xffffu) | (tg << 16)) << 32);
      __hip_atomic_store(&hT[(size_t)(dir * NSD + sid) * 512 + m * 16 + cc], pub,
                         __ATOMIC_RELAXED, __HIP_MEMORY_SCOPE_AGENT);
      if (ao) {   // own slice straight to LDS (raw == blended)
        uint32_t hb0 = f2bf(hn0), hb1 = f2bf(hn1);
        uint32_t p0 = (uint32_t)__shfl_xor((int)hb0, 1);
        uint32_t p1 = (uint32_t)__shfl_xor((int)hb1, 1);
        if (!(cc & 1)) {
          *(uint32_t*)(smem + F_HF + fragAddr(m, sid * SW + cc))      = (hb0 & 0xffffu) | (p0 << 16);
          *(uint32_t*)(smem + F_HF + fragAddr(m, sid * SW + cc + 16)) = (hb1 & 0xffffu) | (p1 << 16);
        }
      }
    }

    // ---- [D] shadow: outs, prefetch, Us GEMM ----
    const int tact = dir ? (SS - 1 - t) : t;
    {
      const size_t ob = ((size_t)tact * BB + m) * (2 * HH) + (size_t)dir * HH + sid * SW + cc;
      __builtin_nontemporal_store(hbl0, &out[ob]);
      __builtin_nontemporal_store(hbl1, &out[ob + 16]);
      const float cb0 = c0reg, cb1 = c1reg;
      __builtin_nontemporal_store(cb0, &out[ob + 8388608]);
      __builtin_nontemporal_store(cb1, &out[ob + 16 + 8388608]);
    }
    u16x4 nxa = {0, 0, 0, 0}, nxb = {0, 0, 0, 0};
    if (t + 1 < SS) {
      const int ta = dir ? (SS - 2 - t) : (t + 1);
      nxa = *(const u16x4*)(xz + (((size_t)dir * SS + ta) * H4 + zc0) * BB + mt * 16 + lq * 4);
      nxb = *(const u16x4*)(xz + (((size_t)dir * SS + ta) * H4 + zc0 + 16) * BB + mt * 16 + lq * 4);
      float mr = 0.f;
      if (tid < 32) mr = mask[(size_t)tid * SS + ta];
      if (w == 0) {
        if (tid < 32) ((float*)(smem + F_MB))[(par ^ 1) * 32 + tid] = mr;
        bool p = (lane < 32) ? (mr == 1.f) : true;
        ull bal = __ballot(p);
        if (lane == 0) ((int*)(smem + F_MB + 256))[par ^ 1] = (bal == ~0ull) ? 1 : 0;
      }
    }
    if (w < 4) {   // us = s_t @ Us
      f32x4 accU = {0.f, 0.f, 0.f, 0.f};
      #pragma unroll
      for (int kk = 0; kk < 8; ++kk) {
        bf16x8 as = *(const bf16x8*)(smem + F_SF + ((mtU * 8 + kk) << 10) + lane * 16);
        accU = mfma16(as, UF[kk], accU);
      }
      float* us = (float*)(smem + F_US);
      #pragma unroll
      for (int i = 0; i < 4; ++i)
        us[(mtU * 16 + lq * 4 + i) * 33 + ntU * 16 + lr] = accU[i];
    }

    // ---- [E] consume h_new (tag t+1) ----
    if (!ao) __syncthreads();   // generic: [C] HF reads must finish before overwrite
    uint32_t stOld[8];
    if (!(ao && w == sid)) {
      const ull* src = hT + (size_t)(dir * NSD + w) * 512;
      consume_tagged(src, smem + F_HF, w, lane, (uint32_t)(t + 1), false, nullptr, !ao, stOld);
    }
    __syncthreads();   // B3

    // ---- [F] uh = h_new @ Uh (waves 4..7) ----
    if (w >= 4) {
      f32x4 accU = {0.f, 0.f, 0.f, 0.f};
      #pragma unroll
      for (int kk = 0; kk < 8; ++kk) {
        bf16x8 ah = *(const bf16x8*)(smem + F_HF + ((mtU * 8 + kk) << 10) + lane * 16);
        accU = mfma16(ah, UF[kk], accU);
      }
      float* uh = (float*)(smem + F_UH);
      #pragma unroll
      for (int i = 0; i < 4; ++i)
        uh[(mtU * 16 + lq * 4 + i) * 33 + ntU * 16 + lr] = accU[i];
    }
    __syncthreads();   // B4
    if (!ao) {         // blend HF -> h_{t+1}
      reblend_tagged(smem + F_HF, w, lane, mb, stOld);
      __syncthreads();
    }

    // ---- [G] s-tail: s_new, tagged publish, own SF write, s_out ----
    {
      const float* us = (const float*)(smem + F_US);
      const float* uh = (const float*)(smem + F_UH);
      const float sv0 = us[m * 33 + cc]      + uh[m * 33 + cc]      + bs0;
      const float sv1 = us[m * 33 + cc + 16] + uh[m * 33 + cc + 16] + bs1;
      const float sn0 = tanhfast(sv0);
      const float sn1 = tanhfast(sv1);
      if (t + 1 < SS) {
        const uint32_t tg = (uint32_t)(t + 1);
        ull pub = (ull)((f2bf(sn0) & 0xffffu) | (tg << 16))
                | ((ull)((f2bf(sn1) & 0xffffu) | (tg << 16)) << 32);
        __hip_atomic_store(&sT[(size_t)(dir * NSD + sid) * 512 + m * 16 + cc], pub,
                           __ATOMIC_RELAXED, __HIP_MEMORY_SCOPE_AGENT);
      }
      float sbl0 = sn0, sbl1 = sn1;
      if (!ao) {
        const float mval = mb[m];
        const float so0 = bf2f(*(const uint16_t*)(smem + F_SF + fragAddr(m, sid * SW + cc)));
        const float so1 = bf2f(*(const uint16_t*)(smem + F_SF + fragAddr(m, sid * SW + cc + 16)));
        sbl0 = mval * sn0 + (1.f - mval) * so0;
        sbl1 = mval * sn1 + (1.f - mval) * so1;
      }
      const size_t obS = ((size_t)tact * BB + m) * (2 * HH) + (size_t)dir * HH + sid * SW + cc + 16777216;
      __builtin_nontemporal_store(sbl0, &out[obS]);
      __builtin_nontemporal_store(sbl1, &out[obS + 16]);
      uint32_t sb0 = f2bf(sbl0), sb1 = f2bf(sbl1);
      uint32_t p0 = (uint32_t)__shfl_xor((int)sb0, 1);
      uint32_t p1 = (uint32_t)__shfl_xor((int)sb1, 1);
      if (!(cc & 1)) {
        *(uint32_t*)(smem + F_SF + fragAddr(m, sid * SW + cc))      = (sb0 & 0xffffu) | (p0 << 16);
        *(uint32_t*)(smem + F_SF + fragAddr(m, sid * SW + cc + 16)) = (sb1 & 0xffffu) | (p1 << 16);
      }
    }

    // ---- [H] next accZ = xz_{t+1} + h_{t+1} @ Wh  (overlaps s flight) ----
    if (t + 1 < SS) {
      f32x4 aZ0, aZ1;
      #pragma unroll
      for (int i = 0; i < 4; ++i) { aZ0[i] = bf2f(nxa[i]); aZ1[i] = bf2f(nxb[i]); }
      #pragma unroll
      for (int kk = 0; kk < 8; ++kk) {
        bf16x8 ah = *(const bf16x8*)(smem + F_HF + ((mt * 8 + kk) << 10) + lane * 16);
        aZ0 = mfma16(ah, WhF[0][kk], aZ0);
        aZ1 = mfma16(ah, WhF[1][kk], aZ1);
      }
      accZ0 = aZ0; accZ1 = aZ1;
    }
  }
}

// ============================================================================
// Fallback: proven round-1 kernel (used only if ws too small).
// ============================================================================
__global__ void __launch_bounds__(NTHR)
slstm_persistent(const float* __restrict__ x, const float* __restrict__ mask,
                 const float* Wx_f, const float* Wh_f, const float* Ws_f, const float* b_f,
                 const float* Us_f, const float* Uh_f, const float* bs_f,
                 const float* Wx_r, const float* Wh_r, const float* Ws_r, const float* b_r,
                 const float* Us_r, const float* Uh_r, const float* bs_r,
                 float* __restrict__ out, uint32_t* __restrict__ wsbase) {
  __shared__ __align__(16) char smem[O_SMEM];

  const int bid = blockIdx.x;
  const int dir = bid >> 4;
  const int g   = bid & 15;
  const int tid = threadIdx.x;
  const int w    = tid >> 6;
  const int lane = tid & 63;
  const int lr = lane & 15, lq = lane >> 4;
  const int mt = w & 1;
  const int q  = w >> 1;

  const float* Wx = dir ? Wx_r : Wx_f;
  const float* Wh = dir ? Wh_r : Wh_f;
  const float* Ws = dir ? Ws_r : Ws_f;
  const float* bv = dir ? b_r  : b_f;
  const float* Us = dir ? Us_r : Us_f;
  const float* Uh = dir ? Uh_r : Uh_f;
  const float* bs = dir ? bs_r : bs_f;

  uint32_t* flags = wsbase;
  uint32_t* hbufB = wsbase + 1024;
  uint32_t* sbufB = wsbase + 1024 + 16384;
  uint32_t* flagH = flags + (dir * 2 + 0) * 16 * 16;
  uint32_t* flagS = flags + (dir * 2 + 1) * 16 * 16;

  bf16x8 WxF[8], WhF[8], WsF[8], UF[8];
  {
    const int col = q * HH + g * 16 + lr;
    #pragma unroll
    for (int kk = 0; kk < 8; ++kk) {
      bf16x8 vx, vh, vs;
      #pragma unroll
      for (int i = 0; i < 8; ++i) {
        int k = kk * 32 + lq * 8 + i;
        vx[i] = (short)f2bf(Wx[k * H4 + col]);
        vh[i] = (short)f2bf(Wh[k * H4 + col]);
        vs[i] = (short)f2bf(Ws[k * H4 + col]);
      }
      WxF[kk] = vx; WhF[kk] = vh; WsF[kk] = vs;
    }
  }
  if (w < 4) {
    const float* U = (w < 2) ? Us : Uh;
    const int colU = g * 16 + lr;
    #pragma unroll
    for (int kk = 0; kk < 8; ++kk) {
      bf16x8 vu;
      #pragma unroll
      for (int i = 0; i < 8; ++i) {
        int k = kk * 32 + lq * 8 + i;
        vu[i] = (short)f2bf(U[k * HH + colU]);
      }
      UF[kk] = vu;
    }
  }
  const float breg  = bv[q * HH + g * 16 + lr];
  const float bsreg = bs[g * 16 + (tid & 15)];

  {
    uint4* p = (uint4*)(smem);
    for (int i = tid; i < 2048; i += NTHR) p[i] = make_uint4(0u, 0u, 0u, 0u);
    float* cb = (float*)(smem + O_CB);
    for (int i = tid; i < BB * 16; i += NTHR) cb[i] = 0.f;
  }
  {
    const int ta = dir ? (SS - 1) : 0;
    const int bm = tid >> 4, e0 = (tid & 15) * 16;
    const float* xs = x + ((size_t)bm * SS + ta) * EE + e0;
    float xr0[16];
    #pragma unroll
    for (int i = 0; i < 16; ++i) xr0[i] = xs[i];
    #pragma unroll
    for (int hfi = 0; hfi < 2; ++hfi) {
      bf16x8 vv;
      #pragma unroll
      for (int i = 0; i < 8; ++i) vv[i] = (short)f2bf(xr0[hfi * 8 + i]);
      *(bf16x8*)(smem + O_XB + fragAddr(bm, e0 + hfi * 8)) = vv;
    }
    if (tid < BB) ((float*)(smem + O_MB))[tid] = mask[(size_t)tid * SS + ta];
  }
  __syncthreads();

  for (int t = 0; t < SS; ++t) {
    const int par = t & 1;
    uint32_t* HbufP = hbufB + (dir * 2 + par) * (16 * 256);
    uint32_t* SbufP = sbufB + (dir * 2 + par) * (16 * 256);
    const float* mb = (const float*)(smem + O_MB + par * 128);

    f32x4 accZ; accZ[0] = breg; accZ[1] = breg; accZ[2] = breg; accZ[3] = breg;
    f32x4 accU = {0.f, 0.f, 0.f, 0.f};
    #pragma unroll
    for (int kk = 0; kk < 8; ++kk) {
      const int fb = ((mt * 8 + kk) << 10) + lane * 16;
      bf16x8 ah = *(const bf16x8*)(smem + O_HF + fb);
      bf16x8 as = *(const bf16x8*)(smem + O_SF + fb);
      bf16x8 ax = *(const bf16x8*)(smem + O_XB + fb);
      accZ = mfma16(ax, WxF[kk], accZ);
      accZ = mfma16(ah, WhF[kk], accZ);
      accZ = mfma16(as, WsF[kk], accZ);
      if (w < 2) accU = mfma16(as, UF[kk], accU);
    }

    float xr[16]; float mreg = 0.f;
    if (t + 1 < SS) {
      const int ta = dir ? (SS - 2 - t) : (t + 1);
      const int bm = tid >> 4, e0 = (tid & 15) * 16;
      const float* xs = x + ((size_t)bm * SS + ta) * EE + e0;
      #pragma unroll
      for (int i = 0; i < 16; ++i) xr[i] = xs[i];
      if (tid < BB) mreg = mask[(size_t)tid * SS + ta];
    }

    {
      float* zb = (float*)(smem + O_ZB);
      #pragma unroll
      for (int i = 0; i < 4; ++i)
        zb[(mt * 4 + q) * 256 + (lq * 4 + i) * 16 + lr] = accZ[i];
      if (w < 2) {
        float* ub = (float*)(smem + O_US);
        #pragma unroll
        for (int i = 0; i < 4; ++i)
          ub[mt * 256 + (lq * 4 + i) * 16 + lr] = accU[i];
      }
    }
    __syncthreads();

    const int bm = tid >> 4, cc = tid & 15;
    const int mtL = bm >> 4, rr = bm & 15;
    float mval;
    {
      const float* zb = (const float*)(smem + O_ZB);
      float zi = zb[(mtL * 4 + 0) * 256 + rr * 16 + cc];
      float zf = zb[(mtL * 4 + 1) * 256 + rr * 16 + cc];
      float zg = zb[(mtL * 4 + 2) * 256 + rr * 16 + cc];
      float zo = zb[(mtL * 4 + 3) * 256 + rr * 16 + cc];
      float* cb = (float*)(smem + O_CB);
      float cold = cb[bm * 16 + cc];
      mval = mb[bm];
      float cn = sigm(zf) * cold + sigm(zi) * tanhfast(zg);
      float hnew = sigm(zo) * tanhfast(cn);
      float cbl = mval * cn + (1.f - mval) * cold;
      cb[bm * 16 + cc] = cbl;
      float hold = bf2f(*(const uint16_t*)(smem + O_HF + fragAddr(bm, g * 16 + cc)));
      float hbl = mval * hnew + (1.f - mval) * hold;
      const int tact = dir ? (SS - 1 - t) : t;
      size_t ob = ((size_t)tact * BB + bm) * (2 * HH) + (size_t)dir * HH + g * 16 + cc;
      out[ob] = hbl;
      out[ob + 8388608] = cbl;
      uint32_t hb = f2bf(hnew);
      uint32_t pv = (uint32_t)__shfl_xor((int)hb, 1);
      if ((tid & 1) == 0) {
        uint32_t word = (hb & 0xffffu) | (pv << 16);
        __hip_atomic_store(&HbufP[g * 256 + (tid >> 1)], word,
                           __ATOMIC_RELAXED, __HIP_MEMORY_SCOPE_AGENT);
      }
    }
    __syncthreads();
    if (tid == 0)
      __hip_atomic_store(&flagH[g * 16], (uint32_t)(t + 1),
                         __ATOMIC_RELAXED, __HIP_MEMORY_SCOPE_AGENT);

    uint32_t oldw[2][4];
    #pragma unroll
    for (int ssl = 0; ssl < 2; ++ssl) {
      const int sl = w + ssl * 8;
      if (lane == 0) {
        while (__hip_atomic_load(&flagH[sl * 16], __ATOMIC_RELAXED,
                                 __HIP_MEMORY_SCOPE_AGENT) < (uint32_t)(t + 1)) {}
      }
      const uint32_t* src = HbufP + sl * 256;
      #pragma unroll
      for (int ww = 0; ww < 4; ++ww) {
        const int word = ww * 64 + lane;
        uint32_t v = __hip_atomic_load(&src[word], __ATOMIC_RELAXED, __HIP_MEMORY_SCOPE_AGENT);
        const int mrow = word >> 3, c0 = (word & 7) * 2;
        const int fa = fragAddr(mrow, sl * 16 + c0);
        oldw[ssl][ww] = *(uint32_t*)(smem + O_HF + fa);
        *(uint32_t*)(smem + O_HF + fa) = v;
      }
    }
    __syncthreads();

    if (w == 2 || w == 3) {
      f32x4 aU = {0.f, 0.f, 0.f, 0.f};
      #pragma unroll
      for (int kk = 0; kk < 8; ++kk) {
        bf16x8 ah = *(const bf16x8*)(smem + O_HF + (((w & 1) * 8 + kk) << 10) + lane * 16);
        aU = mfma16(ah, UF[kk], aU);
      }
      float* ub = (float*)(smem + O_UH);
      #pragma unroll
      for (int i = 0; i < 4; ++i)
        ub[(w & 1) * 256 + (lq * 4 + i) * 16 + lr] = aU[i];
    }
    __syncthreads();

    #pragma unroll
    for (int ssl = 0; ssl < 2; ++ssl) {
      const int sl = w + ssl * 8;
      #pragma unroll
      for (int ww = 0; ww < 4; ++ww) {
        const int word = ww * 64 + lane;
        const int mrow = word >> 3, c0 = (word & 7) * 2;
        const int fa = fragAddr(mrow, sl * 16 + c0);
        uint32_t nv = *(uint32_t*)(smem + O_HF + fa);
        uint32_t ov = oldw[ssl][ww];
        float mv = mb[mrow];
        *(uint32_t*)(smem + O_HF + fa) = blend2(nv, ov, mv);
      }
    }
    {
      const float* ub1 = (const float*)(smem + O_US);
      const float* ub2 = (const float*)(smem + O_UH);
      float sv = ub1[mtL * 256 + rr * 16 + cc] + ub2[mtL * 256 + rr * 16 + cc] + bsreg;
      float snew = tanhfast(sv);
      float sold = bf2f(*(const uint16_t*)(smem + O_SF + fragAddr(bm, g * 16 + cc)));
      float sbl = mval * snew + (1.f - mval) * sold;
      const int tact = dir ? (SS - 1 - t) : t;
      out[((size_t)tact * BB + bm) * (2 * HH) + (size_t)dir * HH + g * 16 + cc + 16777216] = sbl;
      uint32_t sb = f2bf(snew);
      uint32_t pv = (uint32_t)__shfl_xor((int)sb, 1);
      if ((tid & 1) == 0) {
        uint32_t word = (sb & 0xffffu) | (pv << 16);
        __hip_atomic_store(&SbufP[g * 256 + (tid >> 1)], word,
                           __ATOMIC_RELAXED, __HIP_MEMORY_SCOPE_AGENT);
      }
    }
    __syncthreads();
    if (tid == 0)
      __hip_atomic_store(&flagS[g * 16], (uint32_t)(t + 1),
                         __ATOMIC_RELAXED, __HIP_MEMORY_SCOPE_AGENT);

    #pragma unroll
    for (int ssl = 0; ssl < 2; ++ssl) {
      const int sl = w + ssl * 8;
      if (lane == 0) {
        while (__hip_atomic_load(&flagS[sl * 16], __ATOMIC_RELAXED,
                                 __HIP_MEMORY_SCOPE_AGENT) < (uint32_t)(t + 1)) {}
      }
      const uint32_t* src = SbufP + sl * 256;
      #pragma unroll
      for (int ww = 0; ww < 4; ++ww) {
        const int word = ww * 64 + lane;
        uint32_t v = __hip_atomic_load(&src[word], __ATOMIC_RELAXED, __HIP_MEMORY_SCOPE_AGENT);
        const int mrow = word >> 3, c0 = (word & 7) * 2;
        const int fa = fragAddr(mrow, sl * 16 + c0);
        uint32_t ov = *(uint32_t*)(smem + O_SF + fa);
        float mv = mb[mrow];
        *(uint32_t*)(smem + O_SF + fa) = blend2(v, ov, mv);
      }
    }
    if (t + 1 < SS) {
      const int bm2 = tid >> 4, e0 = (tid & 15) * 16;
      #pragma unroll
      for (int hfi = 0; hfi < 2; ++hfi) {
        bf16x8 vv;
        #pragma unroll
        for (int i = 0; i < 8; ++i) vv[i] = (short)f2bf(xr[hfi * 8 + i]);
        *(bf16x8*)(smem + O_XB + fragAddr(bm2, e0 + hfi * 8)) = vv;
      }
      float* mbn = (float*)(smem + O_MB + ((t + 1) & 1) * 128);
      if (tid < BB) mbn[tid] = mreg;
    }
    __syncthreads();
  }
}

extern "C" void kernel_launch(void* const* d_in, const int* in_sizes, int n_in,
                              void* d_out, int out_size, void* d_ws, size_t ws_size,
                              hipStream_t stream) {
  (void)in_sizes; (void)n_in; (void)out_size;
  const float* x    = (const float*)d_in[0];
  const float* mask = (const float*)d_in[1];
  const float* Wx_f = (const float*)d_in[3];
  const float* Wh_f = (const float*)d_in[4];
  const float* Ws_f = (const float*)d_in[5];
  const float* b_f  = (const float*)d_in[6];
  const float* Us_f = (const float*)d_in[7];
  const float* Uh_f = (const float*)d_in[8];
  const float* bs_f = (const float*)d_in[9];
  const float* Wx_r = (const float*)d_in[10];
  const float* Wh_r = (const float*)d_in[11];
  const float* Ws_r = (const float*)d_in[12];
  const float* b_r  = (const float*)d_in[13];
  const float* Us_r = (const float*)d_in[14];
  const float* Uh_r = (const float*)d_in[15];
  const float* bs_r = (const float*)d_in[16];
  float* out = (float*)d_out;
  uint32_t* ws = (uint32_t*)d_ws;

  const size_t XZ_WORDS = (size_t)2 * SS * H4 * BB / 2;   // 16777216 u32 (bf16 xz)
  const size_t TBUF_ULL = (size_t)2 * NSD * 512;          // 8192 ull per state
  const size_t need = XZ_WORDS * 4 + 2 * TBUF_ULL * 8;

  if (ws_size >= need) {
    unsigned short* xz = (unsigned short*)ws;
    ull* hT = (ull*)(ws + XZ_WORDS);
    ull* sT = hT + TBUF_ULL;
    zero_words<<<dim3(128), dim3(256), 0, stream>>>((uint32_t*)hT, (int)(2 * TBUF_ULL * 2));
    xz_prepass<<<dim3(256), dim3(512), 0, stream>>>(x, Wx_f, b_f, Wx_r, b_r, xz);
    slstm_fast4<<<dim3(16), dim3(NTHR), 0, stream>>>(
        mask, Wh_f, Ws_f, Us_f, Uh_f, bs_f,
        Wh_r, Ws_r, Us_r, Uh_r, bs_r, xz, out, hT, sT);
  } else {
    init_flags<<<dim3(4), dim3(256), 0, stream>>>(ws);
    slstm_persistent<<<dim3(32), dim3(NTHR), 0, stream>>>(
        x, mask, Wx_f, Wh_f, Ws_f, b_f, Us_f, Uh_f, bs_f,
        Wx_r, Wh_r, Ws_r, b_r, Us_r, Uh_r, bs_r, out, ws);
  }
}

// Round 6
// 2236.720 us; speedup vs baseline: 1.8829x; 1.1518x over previous
//
#include <hip/hip_runtime.h>
#include <stdint.h>

// Problem constants
#define BB   32      // batch
#define SS   512     // seq len
#define EE   256     // input dim
#define HH   256     // hidden
#define H4   1024    // 4*H
#define NTHR 512     // threads per WG (8 waves)

#define NSD  8       // WGs (slices) per direction
#define SW   32      // h-cols per slice

typedef short bf16x8 __attribute__((ext_vector_type(8)));
typedef float f32x4  __attribute__((ext_vector_type(4)));
typedef unsigned short u16x4 __attribute__((ext_vector_type(4)));
typedef unsigned long long ull;

// ---- fast4 LDS offsets ----
#define F_HF  0        // h A-frags, 16KB
#define F_SF  16384    // s A-frags, 16KB
#define F_ZB  32768    // z tiles f32 [8][16][33] = 16896 B
#define F_US  49664    // s@Us f32 [32][33]
#define F_UH  53888    // hnew@Uh f32 [32][33]
#define F_MB  58112    // mask [2][32] f32 + AO int[2]
#define F_SMEM 58384

// ---- fallback (round-1) kernel LDS offsets ----
#define O_HF  0
#define O_SF  16384
#define O_XB  32768
#define O_ZB  49152
#define O_US  57344
#define O_UH  59392
#define O_CB  61440
#define O_MB  63488
#define O_SMEM 63744

__device__ __forceinline__ float bf2f(uint32_t u) {
  union { uint32_t i; float f; } v; v.i = u << 16; return v.f;
}
__device__ __forceinline__ uint32_t f2bf(float f) {
  union { float f; uint32_t i; } v; v.f = f;
  return (v.i + 0x7fffu + ((v.i >> 16) & 1u)) >> 16;
}
// fast sigmoid/tanh: v_exp + v_rcp (no newton-raphson divide chains).
__device__ __forceinline__ float sigm(float x) {
  return __builtin_amdgcn_rcpf(1.f + __expf(-x));
}
__device__ __forceinline__ float tanhfast(float x) {
  return 1.f - 2.f * __builtin_amdgcn_rcpf(1.f + __expf(2.f * x));
}
__device__ __forceinline__ int fragAddr(int m, int k) {
  return (((m >> 4) * 8 + (k >> 5)) << 10) + (((m & 15) + (((k >> 3) & 3) << 4)) << 4) + ((k & 7) << 1);
}
__device__ __forceinline__ f32x4 mfma16(bf16x8 a, bf16x8 b, f32x4 c) {
  return __builtin_amdgcn_mfma_f32_16x16x32_bf16(a, b, c, 0, 0, 0);
}
__device__ __forceinline__ uint32_t blend2(uint32_t nw, uint32_t ow, float mv) {
  float b0 = mv * bf2f(nw & 0xffffu) + (1.f - mv) * bf2f(ow & 0xffffu);
  float b1 = mv * bf2f(nw >> 16)     + (1.f - mv) * bf2f(ow >> 16);
  return (f2bf(b0) & 0xffffu) | (f2bf(b1) << 16);
}

// ---- tagged exchange: word = {v0|tag<<16, v1|tag<<16}; v0 = col cc, v1 = col cc+16 ----
__device__ __forceinline__ void consume_tagged(const ull* __restrict__ src,
                                               char* dstBase, int sl, int lane, uint32_t tg,
                                               bool blendNow, const float* mbv,
                                               bool doStash, uint32_t* stash) {
  const int Lg = lane >> 3;
  const int c0 = (lane & 7) * 2;
  ull dA[4], dB[4];
  bool ok = false;
  while (!ok) {
    ok = true;
    #pragma unroll
    for (int i = 0; i < 4; ++i) {
      const int W = i * 128 + lane * 2;
      dA[i] = __hip_atomic_load(&src[W],     __ATOMIC_RELAXED, __HIP_MEMORY_SCOPE_AGENT);
      dB[i] = __hip_atomic_load(&src[W + 1], __ATOMIC_RELAXED, __HIP_MEMORY_SCOPE_AGENT);
    }
    #pragma unroll
    for (int i = 0; i < 4; ++i) {
      ok &= (((uint32_t)(dA[i] >> 16) & 0xffffu) == tg) & ((uint32_t)(dA[i] >> 48) == tg);
      ok &= (((uint32_t)(dB[i] >> 16) & 0xffffu) == tg) & ((uint32_t)(dB[i] >> 48) == tg);
    }
  }
  #pragma unroll
  for (int i = 0; i < 4; ++i) {
    const int m = i * 8 + Lg;
    uint32_t wa = ((uint32_t)dA[i] & 0xffffu) | (((uint32_t)dB[i] & 0xffffu) << 16);
    uint32_t wb = ((uint32_t)(dA[i] >> 32) & 0xffffu) | (((uint32_t)(dB[i] >> 32) & 0xffffu) << 16);
    char* pa = dstBase + (((m >> 4) * 8 + sl) << 10) + (((m & 15) + 16 * (c0 >> 3)) << 4) + (c0 & 7) * 2;
    char* pb = pa + 512;
    if (doStash) { stash[i * 2] = *(const uint32_t*)pa; stash[i * 2 + 1] = *(const uint32_t*)pb; }
    if (blendNow) {
      const float mv = mbv[m];
      wa = blend2(wa, *(const uint32_t*)pa, mv);
      wb = blend2(wb, *(const uint32_t*)pb, mv);
    }
    *(uint32_t*)pa = wa;
    *(uint32_t*)pb = wb;
  }
}

__device__ __forceinline__ void reblend_tagged(char* dstBase, int sl, int lane,
                                               const float* mbv, const uint32_t* stash) {
  const int Lg = lane >> 3;
  const int c0 = (lane & 7) * 2;
  #pragma unroll
  for (int i = 0; i < 4; ++i) {
    const int m = i * 8 + Lg;
    char* pa = dstBase + (((m >> 4) * 8 + sl) << 10) + (((m & 15) + 16 * (c0 >> 3)) << 4) + (c0 & 7) * 2;
    char* pb = pa + 512;
    const float mv = mbv[m];
    *(uint32_t*)pa = blend2(*(const uint32_t*)pa, stash[i * 2],     mv);
    *(uint32_t*)pb = blend2(*(const uint32_t*)pb, stash[i * 2 + 1], mv);
  }
}

__global__ void init_flags(uint32_t* f) {
  int i = blockIdx.x * blockDim.x + threadIdx.x;
  if (i < 1024) f[i] = 0u;
}
__global__ void zero_words(uint32_t* p, int n) {
  int i = blockIdx.x * blockDim.x + threadIdx.x;
  if (i < n) p[i] = 0u;
}

// ============================================================================
// Pre-pass v2: weight-resident. 256 blocks = 2 dir x 8 colgroups x 16 tgroups.
// Each wave holds its 16-col Wx B-frag in registers; streams 32 timesteps.
// XZ[dir][t][col][b] = (x[b,t,:] @ Wx + b)[col]  (bf16)
// ============================================================================
__global__ void __launch_bounds__(512)
xz_prepass2(const float* __restrict__ x,
            const float* __restrict__ Wx_f, const float* __restrict__ b_f,
            const float* __restrict__ Wx_r, const float* __restrict__ b_r,
            unsigned short* __restrict__ xz) {
  __shared__ __align__(16) char smem[16384];
  const int bid = blockIdx.x;          // 0..255
  const int dir = bid >> 7;
  const int cg  = (bid >> 4) & 7;
  const int tg  = bid & 15;
  const int tid = threadIdx.x;
  const int w = tid >> 6, lane = tid & 63;
  const int lr = lane & 15, lq = lane >> 4;
  const float* W  = dir ? Wx_r : Wx_f;
  const float* bv = dir ? b_r  : b_f;

  const int col = (cg * 8 + w) * 16 + lr;
  const float breg = bv[col];

  // persistent Wx B-frag for this wave's 16 columns (loaded ONCE)
  bf16x8 WxT[8];
  #pragma unroll
  for (int kk = 0; kk < 8; ++kk) {
    bf16x8 v;
    #pragma unroll
    for (int i = 0; i < 8; ++i)
      v[i] = (short)f2bf(W[(size_t)(kk * 32 + lq * 8 + i) * H4 + col]);
    WxT[kk] = v;
  }

  const int bm = tid >> 4, e0 = (tid & 15) * 16;
  // t order: dir0 ascending from tg*32; dir1 descending from 511-tg*32
  // (order within kernel irrelevant; kept simple)
  // ---- stage t index 0 ----
  {
    const int ta = dir ? (511 - tg * 32) : (tg * 32);
    const float4* xs4 = (const float4*)(x + ((size_t)bm * SS + ta) * EE + e0);
    float xr[16];
    #pragma unroll
    for (int v4 = 0; v4 < 4; ++v4) {
      float4 xv = xs4[v4];
      xr[v4 * 4 + 0] = xv.x; xr[v4 * 4 + 1] = xv.y;
      xr[v4 * 4 + 2] = xv.z; xr[v4 * 4 + 3] = xv.w;
    }
    bf16x8 v0, v1;
    #pragma unroll
    for (int i = 0; i < 8; ++i) { v0[i] = (short)f2bf(xr[i]); v1[i] = (short)f2bf(xr[8 + i]); }
    *(bf16x8*)(smem + fragAddr(bm, e0))     = v0;
    *(bf16x8*)(smem + fragAddr(bm, e0 + 8)) = v1;
  }
  __syncthreads();

  for (int ti = 0; ti < 32; ++ti) {
    const int ta = dir ? (511 - tg * 32 - ti) : (tg * 32 + ti);
    // prefetch next x into regs (hides under MFMA)
    float xr[16];
    if (ti + 1 < 32) {
      const int tn = dir ? (ta - 1) : (ta + 1);
      const float4* xs4 = (const float4*)(x + ((size_t)bm * SS + tn) * EE + e0);
      #pragma unroll
      for (int v4 = 0; v4 < 4; ++v4) {
        float4 xv = xs4[v4];
        xr[v4 * 4 + 0] = xv.x; xr[v4 * 4 + 1] = xv.y;
        xr[v4 * 4 + 2] = xv.z; xr[v4 * 4 + 3] = xv.w;
      }
    }
    // compute 32x16 z-slice for this t
    f32x4 acc0 = {breg, breg, breg, breg};
    f32x4 acc1 = {breg, breg, breg, breg};
    #pragma unroll
    for (int kk = 0; kk < 8; ++kk) {
      bf16x8 a0 = *(const bf16x8*)(smem + (kk << 10) + lane * 16);
      bf16x8 a1 = *(const bf16x8*)(smem + ((8 + kk) << 10) + lane * 16);
      acc0 = mfma16(a0, WxT[kk], acc0);
      acc1 = mfma16(a1, WxT[kk], acc1);
    }
    {
      u16x4 p0, p1;
      #pragma unroll
      for (int i = 0; i < 4; ++i) {
        p0[i] = (unsigned short)f2bf(acc0[i]);
        p1[i] = (unsigned short)f2bf(acc1[i]);
      }
      unsigned short* dst = xz + ((size_t)(dir * SS + ta) * H4 + col) * BB + lq * 4;
      *(u16x4*)dst        = p0;
      *(u16x4*)(dst + 16) = p1;
    }
    __syncthreads();            // all reads of current x-frags done
    if (ti + 1 < 32) {
      bf16x8 v0, v1;
      #pragma unroll
      for (int i = 0; i < 8; ++i) { v0[i] = (short)f2bf(xr[i]); v1[i] = (short)f2bf(xr[8 + i]); }
      *(bf16x8*)(smem + fragAddr(bm, e0))     = v0;
      *(bf16x8*)(smem + fragAddr(bm, e0 + 8)) = v1;
    }
    __syncthreads();            // new frags visible
  }
}

// ============================================================================
// fast4 (proven r5): 8 WGs/dir, 2 hops, tagged flagless exchange,
// 4 barriers/step fast path, own-slice shortcuts, c-state in registers.
// ============================================================================
__global__ void __launch_bounds__(NTHR)
slstm_fast4(const float* __restrict__ mask,
            const float* Wh_f, const float* Ws_f,
            const float* Us_f, const float* Uh_f, const float* bs_f,
            const float* Wh_r, const float* Ws_r,
            const float* Us_r, const float* Uh_r, const float* bs_r,
            const unsigned short* __restrict__ xz,
            float* __restrict__ out,
            ull* __restrict__ hT, ull* __restrict__ sT) {
  __shared__ __align__(16) char smem[F_SMEM];

  const int bid = blockIdx.x;    // 0..15
  const int dir = bid >> 3;
  const int sid = bid & 7;       // slice: cols [sid*32, sid*32+32)
  const int tid = threadIdx.x;
  const int w = tid >> 6;
  const int lane = tid & 63;
  const int lr = lane & 15, lq = lane >> 4;
  const int mt = w & 1, q = w >> 1;

  const float* Wh = dir ? Wh_r : Wh_f;
  const float* Ws = dir ? Ws_r : Ws_f;
  const float* Us = dir ? Us_r : Us_f;
  const float* Uh = dir ? Uh_r : Uh_f;
  const float* bs = dir ? bs_r : bs_f;

  // ---- persistent weight fragments ----
  bf16x8 WhF[2][8], WsF[2][8], UF[8];
  #pragma unroll
  for (int nt = 0; nt < 2; ++nt) {
    const int col = q * HH + sid * SW + nt * 16 + lr;
    #pragma unroll
    for (int kk = 0; kk < 8; ++kk) {
      bf16x8 vh, vs;
      #pragma unroll
      for (int i = 0; i < 8; ++i) {
        const int k = kk * 32 + lq * 8 + i;
        vh[i] = (short)f2bf(Wh[(size_t)k * H4 + col]);
        vs[i] = (short)f2bf(Ws[(size_t)k * H4 + col]);
      }
      WhF[nt][kk] = vh; WsF[nt][kk] = vs;
    }
  }
  const int mtU = (w & 3) >> 1, ntU = w & 1;
  {
    const float* U = (w < 4) ? Us : Uh;
    const int colU = sid * SW + ntU * 16 + lr;
    #pragma unroll
    for (int kk = 0; kk < 8; ++kk) {
      bf16x8 vu;
      #pragma unroll
      for (int i = 0; i < 8; ++i) {
        const int k = kk * 32 + lq * 8 + i;
        vu[i] = (short)f2bf(U[(size_t)k * HH + colU]);
      }
      UF[kk] = vu;
    }
  }
  const float bs0 = bs[sid * SW + (tid & 15)];
  const float bs1 = bs[sid * SW + (tid & 15) + 16];

  // ---- zero HF/SF ----
  {
    uint4* p = (uint4*)smem;
    for (int i = tid; i < 2048; i += NTHR) p[i] = make_uint4(0u, 0u, 0u, 0u);
  }
  // ---- mask_0 / AO_0 / accZ_0 ----
  const int ta0 = dir ? (SS - 1) : 0;
  {
    float mr = 0.f;
    if (tid < 32) mr = mask[(size_t)tid * SS + ta0];
    if (w == 0) {
      if (tid < 32) ((float*)(smem + F_MB))[tid] = mr;
      bool p = (lane < 32) ? (mr == 1.f) : true;
      ull bal = __ballot(p);
      if (lane == 0) ((int*)(smem + F_MB + 256))[0] = (bal == ~0ull) ? 1 : 0;
    }
  }
  const int zc0 = q * HH + sid * SW + lr;
  f32x4 accZ0, accZ1;
  {
    u16x4 xa = *(const u16x4*)(xz + (((size_t)dir * SS + ta0) * H4 + zc0) * BB + mt * 16 + lq * 4);
    u16x4 xb = *(const u16x4*)(xz + (((size_t)dir * SS + ta0) * H4 + zc0 + 16) * BB + mt * 16 + lq * 4);
    #pragma unroll
    for (int i = 0; i < 4; ++i) { accZ0[i] = bf2f(xa[i]); accZ1[i] = bf2f(xb[i]); }
  }
  float c0reg = 0.f, c1reg = 0.f;
  __syncthreads();

  const int m = tid >> 4, cc = tid & 15;
  const int mtL = m >> 4, rr = m & 15;

  for (int t = 0; t < SS; ++t) {
    const int par = t & 1;
    const float* mb  = (const float*)(smem + F_MB) + par * 32;
    const float* mbp = (const float*)(smem + F_MB) + (par ^ 1) * 32;
    const bool ao  = ((const int*)(smem + F_MB + 256))[par] != 0;
    const bool aop = ((const int*)(smem + F_MB + 256))[par ^ 1] != 0;

    // ---- [A] consume s_t (tag t), skip own slice ----
    if (t > 0 && w != sid) {
      const ull* src = sT + (size_t)(dir * NSD + w) * 512;
      consume_tagged(src, smem + F_SF, w, lane, (uint32_t)t, !aop, mbp, false, nullptr);
    }
    __syncthreads();   // B1

    // ---- [B] accZ += s_t @ Ws ; spill z ----
    #pragma unroll
    for (int kk = 0; kk < 8; ++kk) {
      bf16x8 as = *(const bf16x8*)(smem + F_SF + ((mt * 8 + kk) << 10) + lane * 16);
      accZ0 = mfma16(as, WsF[0][kk], accZ0);
      accZ1 = mfma16(as, WsF[1][kk], accZ1);
    }
    {
      float* zb = (float*)(smem + F_ZB);
      const int base = (mt * 4 + q) * 528;
      #pragma unroll
      for (int i = 0; i < 4; ++i) {
        zb[base + (lq * 4 + i) * 33 + lr]      = accZ0[i];
        zb[base + (lq * 4 + i) * 33 + 16 + lr] = accZ1[i];
      }
    }
    __syncthreads();   // B2

    // ---- [C] gates + tagged publish h_new (+ own HF write in fast path) ----
    float hbl0, hbl1;
    {
      const float* zb = (const float*)(smem + F_ZB);
      float hn0, hn1;
      #pragma unroll
      for (int half = 0; half < 2; ++half) {
        const int n = cc + half * 16;
        const float z_i = zb[(mtL * 4 + 0) * 528 + rr * 33 + n];
        const float z_f = zb[(mtL * 4 + 1) * 528 + rr * 33 + n];
        const float z_g = zb[(mtL * 4 + 2) * 528 + rr * 33 + n];
        const float z_o = zb[(mtL * 4 + 3) * 528 + rr * 33 + n];
        const float cold = half ? c1reg : c0reg;
        const float cn = sigm(z_f) * cold + sigm(z_i) * tanhfast(z_g);
        const float hn = sigm(z_o) * tanhfast(cn);
        float cblv, hblv;
        if (ao) { cblv = cn; hblv = hn; }
        else {
          const float mval = mb[m];
          cblv = mval * cn + (1.f - mval) * cold;
          const float hold = bf2f(*(const uint16_t*)(smem + F_HF + fragAddr(m, sid * SW + n)));
          hblv = mval * hn + (1.f - mval) * hold;
        }
        if (half == 0) { c0reg = cblv; hn0 = hn; hbl0 = hblv; }
        else           { c1reg = cblv; hn1 = hn; hbl1 = hblv; }
      }
      const uint32_t tg = (uint32_t)(t + 1);
      ull pub = (ull)((f2bf(hn0) & 0xffffu) | (tg << 16))
              | ((ull)((f2bf(hn1) & 0xffffu) | (tg << 16)) << 32);
      __hip_atomic_store(&hT[(size_t)(dir * NSD + sid) * 512 + m * 16 + cc], pub,
                         __ATOMIC_RELAXED, __HIP_MEMORY_SCOPE_AGENT);
      if (ao) {   // own slice straight to LDS (raw == blended)
        uint32_t hb0 = f2bf(hn0), hb1 = f2bf(hn1);
        uint32_t p0 = (uint32_t)__shfl_xor((int)hb0, 1);
        uint32_t p1 = (uint32_t)__shfl_xor((int)hb1, 1);
        if (!(cc & 1)) {
          *(uint32_t*)(smem + F_HF + fragAddr(m, sid * SW + cc))      = (hb0 & 0xffffu) | (p0 << 16);
          *(uint32_t*)(smem + F_HF + fragAddr(m, sid * SW + cc + 16)) = (hb1 & 0xffffu) | (p1 << 16);
        }
      }
    }

    // ---- [D] shadow: outs, prefetch, Us GEMM ----
    const int tact = dir ? (SS - 1 - t) : t;
    {
      const size_t ob = ((size_t)tact * BB + m) * (2 * HH) + (size_t)dir * HH + sid * SW + cc;
      __builtin_nontemporal_store(hbl0, &out[ob]);
      __builtin_nontemporal_store(hbl1, &out[ob + 16]);
      const float cb0 = c0reg, cb1 = c1reg;
      __builtin_nontemporal_store(cb0, &out[ob + 8388608]);
      __builtin_nontemporal_store(cb1, &out[ob + 16 + 8388608]);
    }
    u16x4 nxa = {0, 0, 0, 0}, nxb = {0, 0, 0, 0};
    if (t + 1 < SS) {
      const int ta = dir ? (SS - 2 - t) : (t + 1);
      nxa = *(const u16x4*)(xz + (((size_t)dir * SS + ta) * H4 + zc0) * BB + mt * 16 + lq * 4);
      nxb = *(const u16x4*)(xz + (((size_t)dir * SS + ta) * H4 + zc0 + 16) * BB + mt * 16 + lq * 4);
      float mr = 0.f;
      if (tid < 32) mr = mask[(size_t)tid * SS + ta];
      if (w == 0) {
        if (tid < 32) ((float*)(smem + F_MB))[(par ^ 1) * 32 + tid] = mr;
        bool p = (lane < 32) ? (mr == 1.f) : true;
        ull bal = __ballot(p);
        if (lane == 0) ((int*)(smem + F_MB + 256))[par ^ 1] = (bal == ~0ull) ? 1 : 0;
      }
    }
    if (w < 4) {   // us = s_t @ Us
      f32x4 accU = {0.f, 0.f, 0.f, 0.f};
      #pragma unroll
      for (int kk = 0; kk < 8; ++kk) {
        bf16x8 as = *(const bf16x8*)(smem + F_SF + ((mtU * 8 + kk) << 10) + lane * 16);
        accU = mfma16(as, UF[kk], accU);
      }
      float* us = (float*)(smem + F_US);
      #pragma unroll
      for (int i = 0; i < 4; ++i)
        us[(mtU * 16 + lq * 4 + i) * 33 + ntU * 16 + lr] = accU[i];
    }

    // ---- [E] consume h_new (tag t+1) ----
    if (!ao) __syncthreads();   // generic: [C] HF reads must finish before overwrite
    uint32_t stOld[8];
    if (!(ao && w == sid)) {
      const ull* src = hT + (size_t)(dir * NSD + w) * 512;
      consume_tagged(src, smem + F_HF, w, lane, (uint32_t)(t + 1), false, nullptr, !ao, stOld);
    }
    __syncthreads();   // B3

    // ---- [F] uh = h_new @ Uh (waves 4..7) ----
    if (w >= 4) {
      f32x4 accU = {0.f, 0.f, 0.f, 0.f};
      #pragma unroll
      for (int kk = 0; kk < 8; ++kk) {
        bf16x8 ah = *(const bf16x8*)(smem + F_HF + ((mtU * 8 + kk) << 10) + lane * 16);
        accU = mfma16(ah, UF[kk], accU);
      }
      float* uh = (float*)(smem + F_UH);
      #pragma unroll
      for (int i = 0; i < 4; ++i)
        uh[(mtU * 16 + lq * 4 + i) * 33 + ntU * 16 + lr] = accU[i];
    }
    __syncthreads();   // B4
    if (!ao) {         // blend HF -> h_{t+1}
      reblend_tagged(smem + F_HF, w, lane, mb, stOld);
      __syncthreads();
    }

    // ---- [G] s-tail: s_new, tagged publish, own SF write, s_out ----
    {
      const float* us = (const float*)(smem + F_US);
      const float* uh = (const float*)(smem + F_UH);
      const float sv0 = us[m * 33 + cc]      + uh[m * 33 + cc]      + bs0;
      const float sv1 = us[m * 33 + cc + 16] + uh[m * 33 + cc + 16] + bs1;
      const float sn0 = tanhfast(sv0);
      const float sn1 = tanhfast(sv1);
      if (t + 1 < SS) {
        const uint32_t tg = (uint32_t)(t + 1);
        ull pub = (ull)((f2bf(sn0) & 0xffffu) | (tg << 16))
                | ((ull)((f2bf(sn1) & 0xffffu) | (tg << 16)) << 32);
        __hip_atomic_store(&sT[(size_t)(dir * NSD + sid) * 512 + m * 16 + cc], pub,
                           __ATOMIC_RELAXED, __HIP_MEMORY_SCOPE_AGENT);
      }
      float sbl0 = sn0, sbl1 = sn1;
      if (!ao) {
        const float mval = mb[m];
        const float so0 = bf2f(*(const uint16_t*)(smem + F_SF + fragAddr(m, sid * SW + cc)));
        const float so1 = bf2f(*(const uint16_t*)(smem + F_SF + fragAddr(m, sid * SW + cc + 16)));
        sbl0 = mval * sn0 + (1.f - mval) * so0;
        sbl1 = mval * sn1 + (1.f - mval) * so1;
      }
      const size_t obS = ((size_t)tact * BB + m) * (2 * HH) + (size_t)dir * HH + sid * SW + cc + 16777216;
      __builtin_nontemporal_store(sbl0, &out[obS]);
      __builtin_nontemporal_store(sbl1, &out[obS + 16]);
      uint32_t sb0 = f2bf(sbl0), sb1 = f2bf(sbl1);
      uint32_t p0 = (uint32_t)__shfl_xor((int)sb0, 1);
      uint32_t p1 = (uint32_t)__shfl_xor((int)sb1, 1);
      if (!(cc & 1)) {
        *(uint32_t*)(smem + F_SF + fragAddr(m, sid * SW + cc))      = (sb0 & 0xffffu) | (p0 << 16);
        *(uint32_t*)(smem + F_SF + fragAddr(m, sid * SW + cc + 16)) = (sb1 & 0xffffu) | (p1 << 16);
      }
    }

    // ---- [H] next accZ = xz_{t+1} + h_{t+1} @ Wh  (overlaps s flight) ----
    if (t + 1 < SS) {
      f32x4 aZ0, aZ1;
      #pragma unroll
      for (int i = 0; i < 4; ++i) { aZ0[i] = bf2f(nxa[i]); aZ1[i] = bf2f(nxb[i]); }
      #pragma unroll
      for (int kk = 0; kk < 8; ++kk) {
        bf16x8 ah = *(const bf16x8*)(smem + F_HF + ((mt * 8 + kk) << 10) + lane * 16);
        aZ0 = mfma16(ah, WhF[0][kk], aZ0);
        aZ1 = mfma16(ah, WhF[1][kk], aZ1);
      }
      accZ0 = aZ0; accZ1 = aZ1;
    }
  }
}

// ============================================================================
// Fallback: proven round-1 kernel (used only if ws too small).
// ============================================================================
__global__ void __launch_bounds__(NTHR)
slstm_persistent(const float* __restrict__ x, const float* __restrict__ mask,
                 const float* Wx_f, const float* Wh_f, const float* Ws_f, const float* b_f,
                 const float* Us_f, const float* Uh_f, const float* bs_f,
                 const float* Wx_r, const float* Wh_r, const float* Ws_r, const float* b_r,
                 const float* Us_r, const float* Uh_r, const float* bs_r,
                 float* __restrict__ out, uint32_t* __restrict__ wsbase) {
  __shared__ __align__(16) char smem[O_SMEM];

  const int bid = blockIdx.x;
  const int dir = bid >> 4;
  const int g   = bid & 15;
  const int tid = threadIdx.x;
  const int w    = tid >> 6;
  const int lane = tid & 63;
  const int lr = lane & 15, lq = lane >> 4;
  const int mt = w & 1;
  const int q  = w >> 1;

  const float* Wx = dir ? Wx_r : Wx_f;
  const float* Wh = dir ? Wh_r : Wh_f;
  const float* Ws = dir ? Ws_r : Ws_f;
  const float* bv = dir ? b_r  : b_f;
  const float* Us = dir ? Us_r : Us_f;
  const float* Uh = dir ? Uh_r : Uh_f;
  const float* bs = dir ? bs_r : bs_f;

  uint32_t* flags = wsbase;
  uint32_t* hbufB = wsbase + 1024;
  uint32_t* sbufB = wsbase + 1024 + 16384;
  uint32_t* flagH = flags + (dir * 2 + 0) * 16 * 16;
  uint32_t* flagS = flags + (dir * 2 + 1) * 16 * 16;

  bf16x8 WxF[8], WhF[8], WsF[8], UF[8];
  {
    const int col = q * HH + g * 16 + lr;
    #pragma unroll
    for (int kk = 0; kk < 8; ++kk) {
      bf16x8 vx, vh, vs;
      #pragma unroll
      for (int i = 0; i < 8; ++i) {
        int k = kk * 32 + lq * 8 + i;
        vx[i] = (short)f2bf(Wx[k * H4 + col]);
        vh[i] = (short)f2bf(Wh[k * H4 + col]);
        vs[i] = (short)f2bf(Ws[k * H4 + col]);
      }
      WxF[kk] = vx; WhF[kk] = vh; WsF[kk] = vs;
    }
  }
  if (w < 4) {
    const float* U = (w < 2) ? Us : Uh;
    const int colU = g * 16 + lr;
    #pragma unroll
    for (int kk = 0; kk < 8; ++kk) {
      bf16x8 vu;
      #pragma unroll
      for (int i = 0; i < 8; ++i) {
        int k = kk * 32 + lq * 8 + i;
        vu[i] = (short)f2bf(U[k * HH + colU]);
      }
      UF[kk] = vu;
    }
  }
  const float breg  = bv[q * HH + g * 16 + lr];
  const float bsreg = bs[g * 16 + (tid & 15)];

  {
    uint4* p = (uint4*)(smem);
    for (int i = tid; i < 2048; i += NTHR) p[i] = make_uint4(0u, 0u, 0u, 0u);
    float* cb = (float*)(smem + O_CB);
    for (int i = tid; i < BB * 16; i += NTHR) cb[i] = 0.f;
  }
  {
    const int ta = dir ? (SS - 1) : 0;
    const int bm = tid >> 4, e0 = (tid & 15) * 16;
    const float* xs = x + ((size_t)bm * SS + ta) * EE + e0;
    float xr0[16];
    #pragma unroll
    for (int i = 0; i < 16; ++i) xr0[i] = xs[i];
    #pragma unroll
    for (int hfi = 0; hfi < 2; ++hfi) {
      bf16x8 vv;
      #pragma unroll
      for (int i = 0; i < 8; ++i) vv[i] = (short)f2bf(xr0[hfi * 8 + i]);
      *(bf16x8*)(smem + O_XB + fragAddr(bm, e0 + hfi * 8)) = vv;
    }
    if (tid < BB) ((float*)(smem + O_MB))[tid] = mask[(size_t)tid * SS + ta];
  }
  __syncthreads();

  for (int t = 0; t < SS; ++t) {
    const int par = t & 1;
    uint32_t* HbufP = hbufB + (dir * 2 + par) * (16 * 256);
    uint32_t* SbufP = sbufB + (dir * 2 + par) * (16 * 256);
    const float* mb = (const float*)(smem + O_MB + par * 128);

    f32x4 accZ; accZ[0] = breg; accZ[1] = breg; accZ[2] = breg; accZ[3] = breg;
    f32x4 accU = {0.f, 0.f, 0.f, 0.f};
    #pragma unroll
    for (int kk = 0; kk < 8; ++kk) {
      const int fb = ((mt * 8 + kk) << 10) + lane * 16;
      bf16x8 ah = *(const bf16x8*)(smem + O_HF + fb);
      bf16x8 as = *(const bf16x8*)(smem + O_SF + fb);
      bf16x8 ax = *(const bf16x8*)(smem + O_XB + fb);
      accZ = mfma16(ax, WxF[kk], accZ);
      accZ = mfma16(ah, WhF[kk], accZ);
      accZ = mfma16(as, WsF[kk], accZ);
      if (w < 2) accU = mfma16(as, UF[kk], accU);
    }

    float xr[16]; float mreg = 0.f;
    if (t + 1 < SS) {
      const int ta = dir ? (SS - 2 - t) : (t + 1);
      const int bm = tid >> 4, e0 = (tid & 15) * 16;
      const float* xs = x + ((size_t)bm * SS + ta) * EE + e0;
      #pragma unroll
      for (int i = 0; i < 16; ++i) xr[i] = xs[i];
      if (tid < BB) mreg = mask[(size_t)tid * SS + ta];
    }

    {
      float* zb = (float*)(smem + O_ZB);
      #pragma unroll
      for (int i = 0; i < 4; ++i)
        zb[(mt * 4 + q) * 256 + (lq * 4 + i) * 16 + lr] = accZ[i];
      if (w < 2) {
        float* ub = (float*)(smem + O_US);
        #pragma unroll
        for (int i = 0; i < 4; ++i)
          ub[mt * 256 + (lq * 4 + i) * 16 + lr] = accU[i];
      }
    }
    __syncthreads();

    const int bm = tid >> 4, cc = tid & 15;
    const int mtL = bm >> 4, rr = bm & 15;
    float mval;
    {
      const float* zb = (const float*)(smem + O_ZB);
      float zi = zb[(mtL * 4 + 0) * 256 + rr * 16 + cc];
      float zf = zb[(mtL * 4 + 1) * 256 + rr * 16 + cc];
      float zg = zb[(mtL * 4 + 2) * 256 + rr * 16 + cc];
      float zo = zb[(mtL * 4 + 3) * 256 + rr * 16 + cc];
      float* cb = (float*)(smem + O_CB);
      float cold = cb[bm * 16 + cc];
      mval = mb[bm];
      float cn = sigm(zf) * cold + sigm(zi) * tanhfast(zg);
      float hnew = sigm(zo) * tanhfast(cn);
      float cbl = mval * cn + (1.f - mval) * cold;
      cb[bm * 16 + cc] = cbl;
      float hold = bf2f(*(const uint16_t*)(smem + O_HF + fragAddr(bm, g * 16 + cc)));
      float hbl = mval * hnew + (1.f - mval) * hold;
      const int tact = dir ? (SS - 1 - t) : t;
      size_t ob = ((size_t)tact * BB + bm) * (2 * HH) + (size_t)dir * HH + g * 16 + cc;
      out[ob] = hbl;
      out[ob + 8388608] = cbl;
      uint32_t hb = f2bf(hnew);
      uint32_t pv = (uint32_t)__shfl_xor((int)hb, 1);
      if ((tid & 1) == 0) {
        uint32_t word = (hb & 0xffffu) | (pv << 16);
        __hip_atomic_store(&HbufP[g * 256 + (tid >> 1)], word,
                           __ATOMIC_RELAXED, __HIP_MEMORY_SCOPE_AGENT);
      }
    }
    __syncthreads();
    if (tid == 0)
      __hip_atomic_store(&flagH[g * 16], (uint32_t)(t + 1),
                         __ATOMIC_RELAXED, __HIP_MEMORY_SCOPE_AGENT);

    uint32_t oldw[2][4];
    #pragma unroll
    for (int ssl = 0; ssl < 2; ++ssl) {
      const int sl = w + ssl * 8;
      if (lane == 0) {
        while (__hip_atomic_load(&flagH[sl * 16], __ATOMIC_RELAXED,
                                 __HIP_MEMORY_SCOPE_AGENT) < (uint32_t)(t + 1)) {}
      }
      const uint32_t* src = HbufP + sl * 256;
      #pragma unroll
      for (int ww = 0; ww < 4; ++ww) {
        const int word = ww * 64 + lane;
        uint32_t v = __hip_atomic_load(&src[word], __ATOMIC_RELAXED, __HIP_MEMORY_SCOPE_AGENT);
        const int mrow = word >> 3, c0 = (word & 7) * 2;
        const int fa = fragAddr(mrow, sl * 16 + c0);
        oldw[ssl][ww] = *(uint32_t*)(smem + O_HF + fa);
        *(uint32_t*)(smem + O_HF + fa) = v;
      }
    }
    __syncthreads();

    if (w == 2 || w == 3) {
      f32x4 aU = {0.f, 0.f, 0.f, 0.f};
      #pragma unroll
      for (int kk = 0; kk < 8; ++kk) {
        bf16x8 ah = *(const bf16x8*)(smem + O_HF + (((w & 1) * 8 + kk) << 10) + lane * 16);
        aU = mfma16(ah, UF[kk], aU);
      }
      float* ub = (float*)(smem + O_UH);
      #pragma unroll
      for (int i = 0; i < 4; ++i)
        ub[(w & 1) * 256 + (lq * 4 + i) * 16 + lr] = aU[i];
    }
    __syncthreads();

    #pragma unroll
    for (int ssl = 0; ssl < 2; ++ssl) {
      const int sl = w + ssl * 8;
      #pragma unroll
      for (int ww = 0; ww < 4; ++ww) {
        const int word = ww * 64 + lane;
        const int mrow = word >> 3, c0 = (word & 7) * 2;
        const int fa = fragAddr(mrow, sl * 16 + c0);
        uint32_t nv = *(uint32_t*)(smem + O_HF + fa);
        uint32_t ov = oldw[ssl][ww];
        float mv = mb[mrow];
        *(uint32_t*)(smem + O_HF + fa) = blend2(nv, ov, mv);
      }
    }
    {
      const float* ub1 = (const float*)(smem + O_US);
      const float* ub2 = (const float*)(smem + O_UH);
      float sv = ub1[mtL * 256 + rr * 16 + cc] + ub2[mtL * 256 + rr * 16 + cc] + bsreg;
      float snew = tanhfast(sv);
      float sold = bf2f(*(const uint16_t*)(smem + O_SF + fragAddr(bm, g * 16 + cc)));
      float sbl = mval * snew + (1.f - mval) * sold;
      const int tact = dir ? (SS - 1 - t) : t;
      out[((size_t)tact * BB + bm) * (2 * HH) + (size_t)dir * HH + g * 16 + cc + 16777216] = sbl;
      uint32_t sb = f2bf(snew);
      uint32_t pv = (uint32_t)__shfl_xor((int)sb, 1);
      if ((tid & 1) == 0) {
        uint32_t word = (sb & 0xffffu) | (pv << 16);
        __hip_atomic_store(&SbufP[g * 256 + (tid >> 1)], word,
                           __ATOMIC_RELAXED, __HIP_MEMORY_SCOPE_AGENT);
      }
    }
    __syncthreads();
    if (tid == 0)
      __hip_atomic_store(&flagS[g * 16], (uint32_t)(t + 1),
                         __ATOMIC_RELAXED, __HIP_MEMORY_SCOPE_AGENT);

    #pragma unroll
    for (int ssl = 0; ssl < 2; ++ssl) {
      const int sl = w + ssl * 8;
      if (lane == 0) {
        while (__hip_atomic_load(&flagS[sl * 16], __ATOMIC_RELAXED,
                                 __HIP_MEMORY_SCOPE_AGENT) < (uint32_t)(t + 1)) {}
      }
      const uint32_t* src = SbufP + sl * 256;
      #pragma unroll
      for (int ww = 0; ww < 4; ++ww) {
        const int word = ww * 64 + lane;
        uint32_t v = __hip_atomic_load(&src[word], __ATOMIC_RELAXED, __HIP_MEMORY_SCOPE_AGENT);
        const int mrow = word >> 3, c0 = (word & 7) * 2;
        const int fa = fragAddr(mrow, sl * 16 + c0);
        uint32_t ov = *(uint32_t*)(smem + O_SF + fa);
        float mv = mb[mrow];
        *(uint32_t*)(smem + O_SF + fa) = blend2(v, ov, mv);
      }
    }
    if (t + 1 < SS) {
      const int bm2 = tid >> 4, e0 = (tid & 15) * 16;
      #pragma unroll
      for (int hfi = 0; hfi < 2; ++hfi) {
        bf16x8 vv;
        #pragma unroll
        for (int i = 0; i < 8; ++i) vv[i] = (short)f2bf(xr[hfi * 8 + i]);
        *(bf16x8*)(smem + O_XB + fragAddr(bm2, e0 + hfi * 8)) = vv;
      }
      float* mbn = (float*)(smem + O_MB + ((t + 1) & 1) * 128);
      if (tid < BB) mbn[tid] = mreg;
    }
    __syncthreads();
  }
}

extern "C" void kernel_launch(void* const* d_in, const int* in_sizes, int n_in,
                              void* d_out, int out_size, void* d_ws, size_t ws_size,
                              hipStream_t stream) {
  (void)in_sizes; (void)n_in; (void)out_size;
  const float* x    = (const float*)d_in[0];
  const float* mask = (const float*)d_in[1];
  const float* Wx_f = (const float*)d_in[3];
  const float* Wh_f = (const float*)d_in[4];
  const float* Ws_f = (const float*)d_in[5];
  const float* b_f  = (const float*)d_in[6];
  const float* Us_f = (const float*)d_in[7];
  const float* Uh_f = (const float*)d_in[8];
  const float* bs_f = (const float*)d_in[9];
  const float* Wx_r = (const float*)d_in[10];
  const float* Wh_r = (const float*)d_in[11];
  const float* Ws_r = (const float*)d_in[12];
  const float* b_r  = (const float*)d_in[13];
  const float* Us_r = (const float*)d_in[14];
  const float* Uh_r = (const float*)d_in[15];
  const float* bs_r = (const float*)d_in[16];
  float* out = (float*)d_out;
  uint32_t* ws = (uint32_t*)d_ws;

  const size_t XZ_WORDS = (size_t)2 * SS * H4 * BB / 2;   // 16777216 u32 (bf16 xz)
  const size_t TBUF_ULL = (size_t)2 * NSD * 512;          // 8192 ull per state
  const size_t need = XZ_WORDS * 4 + 2 * TBUF_ULL * 8;

  if (ws_size >= need) {
    unsigned short* xz = (unsigned short*)ws;
    ull* hT = (ull*)(ws + XZ_WORDS);
    ull* sT = hT + TBUF_ULL;
    zero_words<<<dim3(128), dim3(256), 0, stream>>>((uint32_t*)hT, (int)(2 * TBUF_ULL * 2));
    xz_prepass2<<<dim3(256), dim3(512), 0, stream>>>(x, Wx_f, b_f, Wx_r, b_r, xz);
    slstm_fast4<<<dim3(16), dim3(NTHR), 0, stream>>>(
        mask, Wh_f, Ws_f, Us_f, Uh_f, bs_f,
        Wh_r, Ws_r, Us_r, Uh_r, bs_r, xz, out, hT, sT);
  } else {
    init_flags<<<dim3(4), dim3(256), 0, stream>>>(ws);
    slstm_persistent<<<dim3(32), dim3(NTHR), 0, stream>>>(
        x, mask, Wx_f, Wh_f, Ws_f, b_f, Us_f, Uh_f, bs_f,
        Wx_r, Wh_r, Ws_r, b_r, Us_r, Uh_r, bs_r, out, ws);
  }
}